// Round 14
// baseline (1218.043 us; speedup 1.0000x reference)
//
#include <hip/hip_runtime.h>
#include <hip/hip_bf16.h>

typedef short bf16x8 __attribute__((ext_vector_type(8)));
typedef short short4v __attribute__((ext_vector_type(4)));
typedef float f32x4  __attribute__((ext_vector_type(4)));

// ---------- problem constants ----------
static constexpr float SCALE = 0.17677669529663687f; // 32^-0.5

__device__ __forceinline__ void gload_lds16(const void* g, void* l) {
  __builtin_amdgcn_global_load_lds(
      (const __attribute__((address_space(1))) unsigned int*)g,
      (__attribute__((address_space(3))) unsigned int*)l, 16, 0, 0);
}

__device__ __forceinline__ size_t win_to_nat(int t) {
  int win = t / 49; int n = t - win * 49;
  int bb = win >> 6; int wimg = win & 63;
  int hb = wimg >> 3, wb = wimg & 7;
  int nr = n / 7, nc = n - nr * 7;
  int hh = hb * 7 + nr + 3; if (hh >= 56) hh -= 56;
  int ww = wb * 7 + nc + 3; if (ww >= 56) ww -= 56;
  return (size_t)bb * 3136 + (size_t)hh * 56 + ww;
}

__device__ __forceinline__ float gelu_fast(float x) {
  float t = __expf(-1.702f * x);
  return x / (1.f + t);
}

// ---------- LDS-tiled weight transpose+cast ----------
__global__ __launch_bounds__(256)
void k_transpose(const float* __restrict__ W, __hip_bfloat16* __restrict__ Wt,
                 int K, int N) {
  __shared__ float tile[32][33];
  int tx = threadIdx.x & 31, ty = threadIdx.x >> 5;
  int tc = blockIdx.x, tr = blockIdx.y;
#pragma unroll
  for (int r = 0; r < 32; r += 8)
    tile[r + ty][tx] = W[(size_t)(tr * 32 + r + ty) * N + tc * 32 + tx];
  __syncthreads();
#pragma unroll
  for (int r = 0; r < 32; r += 8)
    Wt[(size_t)(tc * 32 + r + ty) * K + tr * 32 + tx] =
        __float2bfloat16(tile[tx][r + ty]);
}

// ---------- LN1 + roll + window partition ----------
__global__ __launch_bounds__(256)
void k_ln1(const float* __restrict__ x, const float* __restrict__ gw,
           const float* __restrict__ bw, __hip_bfloat16* __restrict__ xw) {
  int lane = threadIdx.x & 63;
  int t = blockIdx.x * 4 + (threadIdx.x >> 6);
  size_t nt = win_to_nat(t);
  const float* xr = x + nt * 384;
  float4 a  = *(const float4*)(xr + lane * 4);
  float2 c2 = *(const float2*)(xr + 256 + lane * 2);
  float v[6] = {a.x, a.y, a.z, a.w, c2.x, c2.y};
  int c0 = lane * 4, c1 = 256 + lane * 2;
  int ch[6] = {c0, c0 + 1, c0 + 2, c0 + 3, c1, c1 + 1};
  float s = 0.f, q = 0.f;
#pragma unroll
  for (int i = 0; i < 6; i++) { s += v[i]; q += v[i] * v[i]; }
#pragma unroll
  for (int m = 1; m < 64; m <<= 1) { s += __shfl_xor(s, m); q += __shfl_xor(q, m); }
  float mean = s * (1.f / 384.f);
  float rstd = rsqrtf(q * (1.f / 384.f) - mean * mean + 1e-5f);
  __hip_bfloat16* o = xw + (size_t)t * 384;
#pragma unroll
  for (int i = 0; i < 6; i++)
    o[ch[i]] = __float2bfloat16((v[i] - mean) * rstd * gw[ch[i]] + bw[ch[i]]);
}

// ---------- double LN ----------
__global__ __launch_bounds__(256)
void k_ln2ff(const float* __restrict__ xres, const float* __restrict__ g2,
             const float* __restrict__ b2, const float* __restrict__ gf,
             const float* __restrict__ bf_, __hip_bfloat16* __restrict__ yln) {
  int lane = threadIdx.x & 63;
  int t = blockIdx.x * 4 + (threadIdx.x >> 6);
  const float* xr = xres + (size_t)t * 384;
  float4 a  = *(const float4*)(xr + lane * 4);
  float2 c2 = *(const float2*)(xr + 256 + lane * 2);
  float v[6] = {a.x, a.y, a.z, a.w, c2.x, c2.y};
  int c0 = lane * 4, c1 = 256 + lane * 2;
  int ch[6] = {c0, c0 + 1, c0 + 2, c0 + 3, c1, c1 + 1};
  float s = 0.f, q = 0.f;
#pragma unroll
  for (int i = 0; i < 6; i++) { s += v[i]; q += v[i] * v[i]; }
#pragma unroll
  for (int m = 1; m < 64; m <<= 1) { s += __shfl_xor(s, m); q += __shfl_xor(q, m); }
  float mean = s * (1.f / 384.f);
  float rstd = rsqrtf(q * (1.f / 384.f) - mean * mean + 1e-5f);
  float y1[6];
  s = 0.f; q = 0.f;
#pragma unroll
  for (int i = 0; i < 6; i++) {
    y1[i] = (v[i] - mean) * rstd * g2[ch[i]] + b2[ch[i]];
    s += y1[i]; q += y1[i] * y1[i];
  }
#pragma unroll
  for (int m = 1; m < 64; m <<= 1) { s += __shfl_xor(s, m); q += __shfl_xor(q, m); }
  float m2 = s * (1.f / 384.f);
  float r2 = rsqrtf(q * (1.f / 384.f) - m2 * m2 + 1e-6f);
  __hip_bfloat16* o = yln + (size_t)t * 384;
#pragma unroll
  for (int i = 0; i < 6; i++)
    o[ch[i]] = __float2bfloat16((y1[i] - m2) * r2 * gf[ch[i]] + bf_[ch[i]]);
}

// ---------- wave-autonomous bf16 MFMA GEMM (NO barriers) ----------
// 1 wave per block, wave-private 64x64 tile, BK=32, 3 private LDS buffers
// (24KB -> ~6 blocks/CU). Depth-2 prefetch, per-wave counted vmcnt(8):
// correctness rests only on the per-wave gload_lds -> vmcnt -> ds_read chain
// (m03) - zero inter-wave hazards. TLP across ~6 independent waves/CU hides
// latency instead of a barrier pipeline (R2-R13 lesson: every barrier-coupled
// schedule plateaued at ~1300cy/step regardless of structure).
// B tiles are duplicated per wave (2x staging traffic, still under the
// 56 B/cy/CU L2 port -> ~1.1 PF design ceiling).
// LDS: R11 line-pair map (conflict-free): chunk C -> line=C>>3, slot=C&7,
// s2=slot^(line&7), row=2*line+(s2>>2), kchunk=s2&3. Read slot formula:
// rslot=(g+4*(r16&1))^(r16>>1). Operand-swapped MFMA (4 cols per lane).
enum { EPI_QKV = 0, EPI_PROJ = 1, EPI_FF1 = 2, EPI_FF2 = 3 };

template <int EPI>
__global__ __launch_bounds__(64)
void k_gemm(const __hip_bfloat16* __restrict__ A, const __hip_bfloat16* __restrict__ Wt,
            const float* __restrict__ bias, int K, int nCol, int cpx,
            const float* __restrict__ aux,        // PROJ: x; FF2: x_res
            float* __restrict__ out_f,            // PROJ: x_res; FF2: final out
            __hip_bfloat16* __restrict__ out_b) { // QKV: q base; FF1: hbuf
  __shared__ __hip_bfloat16 LB[12288];   // 24KB: buf i = [i*4096, i*4096+4096): A|B
  int lane = threadIdx.x;                // 64 threads = 1 wave
  int g = lane >> 4, r16 = lane & 15;

  int bid = blockIdx.x;
  int wg = (bid & 7) * cpx + (bid >> 3);   // XCD swizzle (nwg % 8 == 0)
  int rB = wg / nCol;
  int rowBlk = rB * 64;
  int colBlk = (wg - rB * nCol) * 64;

  // staging: pass p covers chunks C = p*64 + lane (256 16B-chunks / 64x32 tile)
  int s2 = (lane & 7) ^ ((lane >> 3) & 7);
  int srow0 = 2 * (lane >> 3) + (s2 >> 2);      // + p*16
  int cch = s2 & 3;
  const __hip_bfloat16* PA = A + (size_t)(rowBlk + srow0) * K + cch * 8;
  const __hip_bfloat16* PB = Wt + (size_t)(colBlk + srow0) * K + cch * 8;

#define STG(NB, T)                                                            \
  {                                                                           \
    int k0s = (T) << 5;                                                       \
    _Pragma("unroll") for (int p = 0; p < 4; p++) {                           \
      gload_lds16(PA + (size_t)p * 16 * K + k0s, &LB[(NB) * 4096 + p * 512]); \
      gload_lds16(PB + (size_t)p * 16 * K + k0s, &LB[(NB) * 4096 + 2048 + p * 512]); \
    }                                                                         \
  }

  // read offsets: row R = mi*16 + r16 -> elem = mi*512 + (r16>>1)*64 + rslot*8
  int rslot = (g + ((r16 & 1) << 2)) ^ (r16 >> 1);
  int aOff = (r16 >> 1) * 64 + rslot * 8;

  f32x4 acc[4][4] = {};
  const int nt = K >> 5;   // 12 or 48 (divisible by 3)

  // prologue: tiles 0 (buf0) and 1 (buf1) in flight (16 loads)
  STG(0, 0)
  STG(1, 1)

#define STEP(CB, SB, T)                                                       \
  {                                                                           \
    if ((T) + 1 < nt) {                                                       \
      asm volatile("s_waitcnt vmcnt(8)" ::: "memory");  /* tile T landed */   \
    } else {                                                                  \
      asm volatile("s_waitcnt vmcnt(0)" ::: "memory");                        \
    }                                                                         \
    bf16x8 a[4], b[4];                                                        \
    _Pragma("unroll") for (int mi = 0; mi < 4; mi++)                          \
      a[mi] = *(const bf16x8*)(&LB[(CB) * 4096 + aOff + mi * 512]);           \
    _Pragma("unroll") for (int ni = 0; ni < 4; ni++)                          \
      b[ni] = *(const bf16x8*)(&LB[(CB) * 4096 + 2048 + aOff + ni * 512]);    \
    if ((T) + 2 < nt) STG(SB, (T) + 2)                                        \
    __builtin_amdgcn_s_setprio(1);                                            \
    _Pragma("unroll") for (int mi = 0; mi < 4; mi++)                          \
      _Pragma("unroll") for (int ni = 0; ni < 4; ni++)                        \
        acc[mi][ni] = __builtin_amdgcn_mfma_f32_16x16x32_bf16(                \
            b[ni], a[mi], acc[mi][ni], 0, 0, 0);                              \
    __builtin_amdgcn_s_setprio(0);                                            \
  }

  for (int t = 0; t < nt; t += 3) {
    STEP(0, 2, t)
    STEP(1, 0, t + 1)
    STEP(2, 1, t + 2)
  }
#undef STEP
#undef STG

  // ---- vectorized epilogue in buf0 region (last compute buf = 2, disjoint) ----
  if constexpr (EPI == EPI_QKV || EPI == EPI_FF1) {
    __hip_bfloat16* EP = LB;              // 64x64 bf16 = 8KB
#pragma unroll
    for (int ni = 0; ni < 4; ni++) {
      float4 b4 = *(const float4*)(bias + colBlk + ni * 16 + g * 4);
#pragma unroll
      for (int mi = 0; mi < 4; mi++) {
        float v0 = acc[mi][ni][0] + b4.x, v1 = acc[mi][ni][1] + b4.y,
              v2 = acc[mi][ni][2] + b4.z, v3 = acc[mi][ni][3] + b4.w;
        if constexpr (EPI == EPI_FF1) {
          v0 = gelu_fast(v0); v1 = gelu_fast(v1);
          v2 = gelu_fast(v2); v3 = gelu_fast(v3);
        }
        short4v s4 = {(short)__bfloat16_as_ushort(__float2bfloat16(v0)),
                      (short)__bfloat16_as_ushort(__float2bfloat16(v1)),
                      (short)__bfloat16_as_ushort(__float2bfloat16(v2)),
                      (short)__bfloat16_as_ushort(__float2bfloat16(v3))};
        int row = mi * 16 + r16;
        int ch8 = (ni * 2 + (g >> 1)) ^ (row & 7);
        *(short4v*)(&EP[row * 64 + ch8 * 8 + (g & 1) * 4]) = s4;
      }
    }
#pragma unroll
    for (int j = 0; j < 8; j++) {
      int r = j * 8 + (lane >> 3);
      bf16x8 vv = *(const bf16x8*)(&EP[r * 64 + ((lane & 7) ^ (r & 7)) * 8]);
      int grow = rowBlk + r;
      int col0 = colBlk + (lane & 7) * 8;
      if constexpr (EPI == EPI_QKV) {
        int winr = grow / 49, nn = grow - winr * 49;
        int which = col0 / 384; int rem = col0 - which * 384;
        int hh = rem >> 5, dd = rem & 31;
        size_t off = (((size_t)winr * 12 + hh) * 49 + nn) * 32 + dd;
        *(bf16x8*)(out_b + (size_t)which * 38535168u + off) = vv;
      } else {
        *(bf16x8*)(out_b + (size_t)grow * 1536 + col0) = vv;
      }
    }
  } else {
    float* EPF = (float*)LB;              // 32x64 f32 = 8KB, 2 half-passes
#pragma unroll
    for (int half = 0; half < 2; half++) {
#pragma unroll
      for (int ni = 0; ni < 4; ni++) {
        float4 b4 = *(const float4*)(bias + colBlk + ni * 16 + g * 4);
#pragma unroll
        for (int mi2 = 0; mi2 < 2; mi2++) {
          int mi = half * 2 + mi2;
          f32x4 v = acc[mi][ni];
          v[0] += b4.x; v[1] += b4.y; v[2] += b4.z; v[3] += b4.w;
          int row = mi2 * 16 + r16;
          int ch4 = (ni * 4 + g) ^ r16;
          *(f32x4*)(&EPF[row * 64 + ch4 * 4]) = v;
        }
      }
#pragma unroll
      for (int j = 0; j < 8; j++) {
        int r = j * 4 + g;
        f32x4 vv = *(const f32x4*)(&EPF[r * 64 + ((r16 ^ (r & 15)) * 4)]);
        int grow = rowBlk + half * 32 + r;
        int col0 = colBlk + r16 * 4;
        if constexpr (EPI == EPI_PROJ) {
          size_t nt2 = win_to_nat(grow);
          const float4 a4 = *(const float4*)(aux + nt2 * 384 + col0);
          float4 o4 = {vv[0] + a4.x, vv[1] + a4.y, vv[2] + a4.z, vv[3] + a4.w};
          *(float4*)(out_f + nt2 * 384 + col0) = o4;
        } else {
          const float4 a4 = *(const float4*)(aux + (size_t)grow * 384 + col0);
          float4 o4 = {vv[0] + a4.x, vv[1] + a4.y, vv[2] + a4.z, vv[3] + a4.w};
          *(float4*)(out_f + (size_t)grow * 384 + col0) = o4;
        }
      }
    }
  }
}

// ---------- windowed attention: 1 wave per (window, head) ----------
__global__ __launch_bounds__(256)
void k_attn(const __hip_bfloat16* __restrict__ q, const __hip_bfloat16* __restrict__ k,
            const __hip_bfloat16* __restrict__ v, const float* __restrict__ rpb,
            __hip_bfloat16* __restrict__ o) {
  __shared__ __hip_bfloat16 P[4][64][72];
  int tid = threadIdx.x;
  int lane = tid & 63, wave = tid >> 6;
  int g = lane >> 4, r16 = lane & 15;
  int gid = blockIdx.x * 4 + wave;
  int wi = gid / 12, h = gid - (gid / 12) * 12;
  int wimg = wi & 63;
  int hb = wimg >> 3, wb = wimg & 7;
  size_t base = ((size_t)wi * 12 + h) * (49 * 32);
  const __hip_bfloat16* qb = q + base;
  const __hip_bfloat16* kb = k + base;
  const __hip_bfloat16* vb = v + base;

  bf16x8 zf = {0, 0, 0, 0, 0, 0, 0, 0};
  bf16x8 qf[4], kf[4];
#pragma unroll
  for (int mi = 0; mi < 4; mi++) {
    int row = mi * 16 + r16;
    qf[mi] = (row < 49) ? *(const bf16x8*)(qb + row * 32 + g * 8) : zf;
    kf[mi] = (row < 49) ? *(const bf16x8*)(kb + row * 32 + g * 8) : zf;
  }
  f32x4 fz = {0.f, 0.f, 0.f, 0.f};
  f32x4 S[4][4];
#pragma unroll
  for (int mi = 0; mi < 4; mi++)
#pragma unroll
    for (int ni = 0; ni < 4; ni++)
      S[mi][ni] = __builtin_amdgcn_mfma_f32_16x16x32_bf16(qf[mi], kf[ni], fz, 0, 0, 0);

  int kiA[4], kjA[4], rkA[4], cvA[4];
#pragma unroll
  for (int ni = 0; ni < 4; ni++) {
    int col = ni * 16 + r16;
    cvA[ni] = (col < 49);
    int ki = col / 7, kj = col - (col / 7) * 7;
    kiA[ni] = ki; kjA[ni] = kj;
    int hg = hb * 7 + ki, wg = wb * 7 + kj;
    int rh = (hg < 49) ? 0 : ((hg < 53) ? 1 : 2);
    int rw = (wg < 49) ? 0 : ((wg < 53) ? 1 : 2);
    rkA[ni] = rh * 3 + rw;
  }

#pragma unroll
  for (int mi = 0; mi < 4; mi++) {
#pragma unroll
    for (int rr = 0; rr < 4; rr++) {
      int row = mi * 16 + g * 4 + rr;
      float sv[4];
      float mx = -1e30f;
      int qi = row / 7, qj = row - (row / 7) * 7;
      int hgq = hb * 7 + qi, wgq = wb * 7 + qj;
      int rhq = (hgq < 49) ? 0 : ((hgq < 53) ? 1 : 2);
      int rwq = (wgq < 49) ? 0 : ((wgq < 53) ? 1 : 2);
      int rq = rhq * 3 + rwq;
#pragma unroll
      for (int ni = 0; ni < 4; ni++) {
        float s = -1e30f;
        if (row < 49 && cvA[ni]) {
          int idx = (qi - kiA[ni] + 6) * 13 + (qj - kjA[ni] + 6);
          float maskv = (rq != rkA[ni]) ? -100.f : 0.f;
          s = S[mi][ni][rr] * SCALE + rpb[idx * 12 + h] + maskv;
        }
        sv[ni] = s;
        mx = fmaxf(mx, s);
      }
#pragma unroll
      for (int m = 1; m <= 8; m <<= 1) mx = fmaxf(mx, __shfl_xor(mx, m));
      float sum = 0.f;
#pragma unroll
      for (int ni = 0; ni < 4; ni++) {
        float p = __expf(sv[ni] - mx);
        sv[ni] = p; sum += p;
      }
#pragma unroll
      for (int m = 1; m <= 8; m <<= 1) sum += __shfl_xor(sum, m);
      float inv = 1.f / sum;
#pragma unroll
      for (int ni = 0; ni < 4; ni++)
        P[wave][row][ni * 16 + r16] = __float2bfloat16(sv[ni] * inv);
    }
  }

  f32x4 O[4][2] = {};
#pragma unroll
  for (int ks = 0; ks < 2; ks++) {
    bf16x8 pf[4];
#pragma unroll
    for (int mi = 0; mi < 4; mi++)
      pf[mi] = *(const bf16x8*)(&P[wave][mi * 16 + r16][ks * 32 + g * 8]);
#pragma unroll
    for (int ni = 0; ni < 2; ni++) {
      bf16x8 vf = zf;
#pragma unroll
      for (int j = 0; j < 8; j++) {
        int m = ks * 32 + g * 8 + j;
        if (m < 49) vf[j] = ((const short*)vb)[m * 32 + ni * 16 + r16];
      }
#pragma unroll
      for (int mi = 0; mi < 4; mi++)
        O[mi][ni] = __builtin_amdgcn_mfma_f32_16x16x32_bf16(pf[mi], vf, O[mi][ni], 0, 0, 0);
    }
  }

#pragma unroll
  for (int mi = 0; mi < 4; mi++)
#pragma unroll
    for (int rr = 0; rr < 4; rr++) {
      int row = mi * 16 + g * 4 + rr;
      if (row < 49) {
#pragma unroll
        for (int ni = 0; ni < 2; ni++) {
          int col = ni * 16 + r16;
          o[(((size_t)wi * 49 + row) * 12 + h) * 32 + col] = __float2bfloat16(O[mi][ni][rr]);
        }
      }
    }
}

// ---------- host launch ----------
extern "C" void kernel_launch(void* const* d_in, const int* in_sizes, int n_in,
                              void* d_out, int out_size, void* d_ws, size_t ws_size,
                              hipStream_t stream) {
  const float* x      = (const float*)d_in[0];
  const float* ln1_g  = (const float*)d_in[1];
  const float* ln1_b  = (const float*)d_in[2];
  const float* qkv_w  = (const float*)d_in[3];
  const float* qkv_b  = (const float*)d_in[4];
  const float* proj_w = (const float*)d_in[5];
  const float* proj_b = (const float*)d_in[6];
  const float* rpb    = (const float*)d_in[7];
  const float* ln2_g  = (const float*)d_in[8];
  const float* ln2_b  = (const float*)d_in[9];
  const float* ffg    = (const float*)d_in[10];
  const float* ffb    = (const float*)d_in[11];
  const float* ff1_w  = (const float*)d_in[12];
  const float* ff1_b  = (const float*)d_in[13];
  const float* ff2_w  = (const float*)d_in[14];
  const float* ff2_b  = (const float*)d_in[15];
  float* out = (float*)d_out;

  char* ws = (char*)d_ws;
  __hip_bfloat16* xw     = (__hip_bfloat16*)ws;
  __hip_bfloat16* qbuf   = (__hip_bfloat16*)(ws + 77070336u);
  __hip_bfloat16* kbuf   = qbuf + 38535168u;
  __hip_bfloat16* vbuf   = kbuf + 38535168u;
  __hip_bfloat16* attn_o = xw;
  __hip_bfloat16* hbuf   = (__hip_bfloat16*)ws;
  float*          x_res  = (float*)(ws + 308281344u);
  __hip_bfloat16* yln    = (__hip_bfloat16*)(ws + 462422016u);
  __hip_bfloat16* qkv_wt = (__hip_bfloat16*)(ws + 539492352u);
  __hip_bfloat16* proj_wt = qkv_wt + 442368u;
  __hip_bfloat16* ff1_wt  = proj_wt + 147456u;
  __hip_bfloat16* ff2_wt  = ff1_wt + 589824u;

  // weight prep
  k_transpose<<<dim3(1152 / 32, 384 / 32), dim3(256), 0, stream>>>(qkv_w, qkv_wt, 384, 1152);
  k_transpose<<<dim3(384 / 32, 384 / 32), dim3(256), 0, stream>>>(proj_w, proj_wt, 384, 384);
  k_transpose<<<dim3(1536 / 32, 384 / 32), dim3(256), 0, stream>>>(ff1_w, ff1_wt, 384, 1536);
  k_transpose<<<dim3(384 / 32, 1536 / 32), dim3(256), 0, stream>>>(ff2_w, ff2_wt, 1536, 384);

  // LN1 + shift + window partition
  k_ln1<<<dim3(25088), dim3(256), 0, stream>>>(x, ln1_g, ln1_b, xw);

  // GEMMs: 64x64 wave tiles. M blocks = 100352/64 = 1568.
  // QKV: nCol = 1152/64 = 18 -> nwg 28224
  k_gemm<EPI_QKV><<<dim3(28224), dim3(64), 0, stream>>>(xw, qkv_wt, qkv_b, 384, 18, 28224 / 8,
                                                        nullptr, nullptr, qbuf);
  // attention
  k_attn<<<dim3(6144), dim3(256), 0, stream>>>(qbuf, kbuf, vbuf, rpb, attn_o);
  // proj: nCol = 6 -> nwg 9408
  k_gemm<EPI_PROJ><<<dim3(9408), dim3(64), 0, stream>>>(attn_o, proj_wt, proj_b, 384, 6, 9408 / 8,
                                                        x, x_res, nullptr);
  // LN2 + ffLN
  k_ln2ff<<<dim3(25088), dim3(256), 0, stream>>>(x_res, ln2_g, ln2_b, ffg, ffb, yln);
  // FF1 + gelu: nCol = 24 -> nwg 37632
  k_gemm<EPI_FF1><<<dim3(37632), dim3(64), 0, stream>>>(yln, ff1_wt, ff1_b, 384, 24, 37632 / 8,
                                                        nullptr, nullptr, hbuf);
  // FF2 + residual: K=1536, nCol = 6 -> nwg 9408
  k_gemm<EPI_FF2><<<dim3(9408), dim3(64), 0, stream>>>(hbuf, ff2_wt, ff2_b, 1536, 6, 9408 / 8,
                                                       x_res, out, nullptr);
}

// Round 15
// 961.135 us; speedup vs baseline: 1.2673x; 1.2673x over previous
//
#include <hip/hip_runtime.h>
#include <hip/hip_bf16.h>

typedef short bf16x8 __attribute__((ext_vector_type(8)));
typedef short short4v __attribute__((ext_vector_type(4)));
typedef float f32x4  __attribute__((ext_vector_type(4)));

// ---------- problem constants ----------
static constexpr float SCALE = 0.17677669529663687f; // 32^-0.5

__device__ __forceinline__ void gload_lds16(const void* g, void* l) {
  __builtin_amdgcn_global_load_lds(
      (const __attribute__((address_space(1))) unsigned int*)g,
      (__attribute__((address_space(3))) unsigned int*)l, 16, 0, 0);
}

__device__ __forceinline__ size_t win_to_nat(int t) {
  int win = t / 49; int n = t - win * 49;
  int bb = win >> 6; int wimg = win & 63;
  int hb = wimg >> 3, wb = wimg & 7;
  int nr = n / 7, nc = n - nr * 7;
  int hh = hb * 7 + nr + 3; if (hh >= 56) hh -= 56;
  int ww = wb * 7 + nc + 3; if (ww >= 56) ww -= 56;
  return (size_t)bb * 3136 + (size_t)hh * 56 + ww;
}

__device__ __forceinline__ float gelu_fast(float x) {
  float t = __expf(-1.702f * x);
  return x / (1.f + t);
}

// ---------- LDS-tiled weight transpose+cast ----------
__global__ __launch_bounds__(256)
void k_transpose(const float* __restrict__ W, __hip_bfloat16* __restrict__ Wt,
                 int K, int N) {
  __shared__ float tile[32][33];
  int tx = threadIdx.x & 31, ty = threadIdx.x >> 5;
  int tc = blockIdx.x, tr = blockIdx.y;
#pragma unroll
  for (int r = 0; r < 32; r += 8)
    tile[r + ty][tx] = W[(size_t)(tr * 32 + r + ty) * N + tc * 32 + tx];
  __syncthreads();
#pragma unroll
  for (int r = 0; r < 32; r += 8)
    Wt[(size_t)(tc * 32 + r + ty) * K + tr * 32 + tx] =
        __float2bfloat16(tile[tx][r + ty]);
}

// ---------- LN1 + roll + window partition ----------
__global__ __launch_bounds__(256)
void k_ln1(const float* __restrict__ x, const float* __restrict__ gw,
           const float* __restrict__ bw, __hip_bfloat16* __restrict__ xw) {
  int lane = threadIdx.x & 63;
  int t = blockIdx.x * 4 + (threadIdx.x >> 6);
  size_t nt = win_to_nat(t);
  const float* xr = x + nt * 384;
  float4 a  = *(const float4*)(xr + lane * 4);
  float2 c2 = *(const float2*)(xr + 256 + lane * 2);
  float v[6] = {a.x, a.y, a.z, a.w, c2.x, c2.y};
  int c0 = lane * 4, c1 = 256 + lane * 2;
  int ch[6] = {c0, c0 + 1, c0 + 2, c0 + 3, c1, c1 + 1};
  float s = 0.f, q = 0.f;
#pragma unroll
  for (int i = 0; i < 6; i++) { s += v[i]; q += v[i] * v[i]; }
#pragma unroll
  for (int m = 1; m < 64; m <<= 1) { s += __shfl_xor(s, m); q += __shfl_xor(q, m); }
  float mean = s * (1.f / 384.f);
  float rstd = rsqrtf(q * (1.f / 384.f) - mean * mean + 1e-5f);
  __hip_bfloat16* o = xw + (size_t)t * 384;
#pragma unroll
  for (int i = 0; i < 6; i++)
    o[ch[i]] = __float2bfloat16((v[i] - mean) * rstd * gw[ch[i]] + bw[ch[i]]);
}

// ---------- double LN ----------
__global__ __launch_bounds__(256)
void k_ln2ff(const float* __restrict__ xres, const float* __restrict__ g2,
             const float* __restrict__ b2, const float* __restrict__ gf,
             const float* __restrict__ bf_, __hip_bfloat16* __restrict__ yln) {
  int lane = threadIdx.x & 63;
  int t = blockIdx.x * 4 + (threadIdx.x >> 6);
  const float* xr = xres + (size_t)t * 384;
  float4 a  = *(const float4*)(xr + lane * 4);
  float2 c2 = *(const float2*)(xr + 256 + lane * 2);
  float v[6] = {a.x, a.y, a.z, a.w, c2.x, c2.y};
  int c0 = lane * 4, c1 = 256 + lane * 2;
  int ch[6] = {c0, c0 + 1, c0 + 2, c0 + 3, c1, c1 + 1};
  float s = 0.f, q = 0.f;
#pragma unroll
  for (int i = 0; i < 6; i++) { s += v[i]; q += v[i] * v[i]; }
#pragma unroll
  for (int m = 1; m < 64; m <<= 1) { s += __shfl_xor(s, m); q += __shfl_xor(q, m); }
  float mean = s * (1.f / 384.f);
  float rstd = rsqrtf(q * (1.f / 384.f) - mean * mean + 1e-5f);
  float y1[6];
  s = 0.f; q = 0.f;
#pragma unroll
  for (int i = 0; i < 6; i++) {
    y1[i] = (v[i] - mean) * rstd * g2[ch[i]] + b2[ch[i]];
    s += y1[i]; q += y1[i] * y1[i];
  }
#pragma unroll
  for (int m = 1; m < 64; m <<= 1) { s += __shfl_xor(s, m); q += __shfl_xor(q, m); }
  float m2 = s * (1.f / 384.f);
  float r2 = rsqrtf(q * (1.f / 384.f) - m2 * m2 + 1e-6f);
  __hip_bfloat16* o = yln + (size_t)t * 384;
#pragma unroll
  for (int i = 0; i < 6; i++)
    o[ch[i]] = __float2bfloat16((y1[i] - m2) * r2 * gf[ch[i]] + bf_[ch[i]]);
}

// ---------- big-wave-tile bf16 MFMA GEMM ----------
// Block 512x128, 8 waves (4M x 2N), WAVE-TILE 128x64 (acc[8][4]) -> LDS
// bytes/MFMA drop 750 -> ~530 (R14 lesson: LDS traffic/MFMA is the invariant
// wall; it scales with Mw+Nw while FLOP scales Mw*Nw).
// BK=32, 3 bufs (A 32KB + B 8KB each) = 120KB. R13-proven single barrier per
// K-tile: vmcnt(5) -> barrier(publish) -> ds_reads -> STG(t+2) -> MFMA.
// 5 uniform gload_lds per thread per tile (A 4 passes x 128 rows, B 1 pass).
// LDS layout (R11 line-pair, conflict-free): chunk C -> line=C>>3, slot=C&7,
// s2=slot^(line&7), row=2*line+(s2>>2), kchunk=s2&3; read slot
// rslot=(g+4*(r16&1))^(r16>>1). Operand-swapped MFMA (4 consecutive cols/lane).
// XCD swizzle: m204 bijective (nwg need not divide 8).
enum { EPI_QKV = 0, EPI_PROJ = 1, EPI_FF1 = 2, EPI_FF2 = 3 };

template <int EPI>
__global__ __launch_bounds__(512, 1)
void k_gemm(const __hip_bfloat16* __restrict__ A, const __hip_bfloat16* __restrict__ Wt,
            const float* __restrict__ bias, int K, int nCol, int nwg,
            const float* __restrict__ aux,        // PROJ: x; FF2: x_res
            float* __restrict__ out_f,            // PROJ: x_res; FF2: final out
            __hip_bfloat16* __restrict__ out_b) { // QKV: q base; FF1: hbuf
  __shared__ __hip_bfloat16 LB[61440];   // 120KB: buf i at i*20480 (A 16384 | B 4096)
  int tid = threadIdx.x;
  int lane = tid & 63, w = tid >> 6;
  int g = lane >> 4, r16 = lane & 15;
  int wr = w >> 1, wc = w & 1;           // 4M x 2N wave grid

  // m204 bijective XCD swizzle
  int bid = blockIdx.x;
  int qch = nwg >> 3, rch = nwg & 7;
  int xcd = bid & 7, idx = bid >> 3;
  int wg = (xcd < rch ? xcd * (qch + 1) : rch * (qch + 1) + (xcd - rch) * qch) + idx;
  int rB = wg / nCol;
  int rowBlk = rB * 512;
  int colBlk = (wg - rB * nCol) * 128;

  // staging map (pass-invariant): s2=(tid&7)^((tid>>3)&7); row0=2*(tid>>3)+(s2>>2)
  int s2 = (tid & 7) ^ ((tid >> 3) & 7);
  int srow = 2 * (tid >> 3) + (s2 >> 2);      // 0..127 within a pass
  int cch = s2 & 3;
  const __hip_bfloat16* PA = A + (size_t)(rowBlk + srow) * K + cch * 8;
  const __hip_bfloat16* PB = Wt + (size_t)(colBlk + srow) * K + cch * 8;

#define STG(NB, T)                                                            \
  {                                                                           \
    int k0s = (T) << 5;                                                       \
    _Pragma("unroll") for (int p = 0; p < 4; p++)                             \
      gload_lds16(PA + (size_t)p * 128 * K + k0s,                             \
                  &LB[(NB) * 20480 + p * 4096 + w * 512]);                    \
    gload_lds16(PB + k0s, &LB[(NB) * 20480 + 16384 + w * 512]);               \
  }

  // read offsets (elements): A frag mi: wr*4096 + mi*512 + (r16>>1)*64 + rslot*8
  int rslot = (g + ((r16 & 1) << 2)) ^ (r16 >> 1);
  int aBase = wr * 4096 + (r16 >> 1) * 64 + rslot * 8;
  int bBase = 16384 + wc * 2048 + (r16 >> 1) * 64 + rslot * 8;

  f32x4 acc[8][4] = {};
  const int nt = K >> 5;   // 12 or 48 (divisible by 3)

  STG(0, 0)
  STG(1, 1)

#define STEP(CB, SB, T)                                                       \
  {                                                                           \
    if ((T) + 1 < nt) {                                                       \
      asm volatile("s_waitcnt vmcnt(5)" ::: "memory");                        \
    } else {                                                                  \
      asm volatile("s_waitcnt vmcnt(0)" ::: "memory");                        \
    }                                                                         \
    __builtin_amdgcn_s_barrier(); /* publish buf CB (tile T) */               \
    asm volatile("" ::: "memory");                                            \
    bf16x8 a[8], b[4];                                                        \
    _Pragma("unroll") for (int mi = 0; mi < 8; mi++)                          \
      a[mi] = *(const bf16x8*)(&LB[(CB) * 20480 + aBase + mi * 512]);         \
    _Pragma("unroll") for (int ni = 0; ni < 4; ni++)                          \
      b[ni] = *(const bf16x8*)(&LB[(CB) * 20480 + bBase + ni * 512]);         \
    if ((T) + 2 < nt) STG(SB, (T) + 2)                                        \
    __builtin_amdgcn_s_setprio(1);                                            \
    _Pragma("unroll") for (int mi = 0; mi < 8; mi++)                          \
      _Pragma("unroll") for (int ni = 0; ni < 4; ni++)                        \
        acc[mi][ni] = __builtin_amdgcn_mfma_f32_16x16x32_bf16(                \
            b[ni], a[mi], acc[mi][ni], 0, 0, 0);                              \
    __builtin_amdgcn_s_setprio(0);                                            \
  }

  for (int t = 0; t < nt; t += 3) {
    STEP(0, 2, t)
    STEP(1, 0, t + 1)
    STEP(2, 1, t + 2)
  }
#undef STEP
#undef STG

  // ---- vectorized epilogue, per-wave LDS region [w*4096, +4096) elems ----
  // region spans elems [0,32768) = bufs 0/1 area; last compute buf = 2 and the
  // last staged buf = 2 -> disjoint; all cross-wave reads of bufs 0/1 retired
  // before the final tile's collective barrier (R13 safety argument).
  if constexpr (EPI == EPI_QKV || EPI == EPI_FF1) {
    __hip_bfloat16* EP = &LB[w * 4096];   // 64x64 bf16, two half-passes
#pragma unroll
    for (int h = 0; h < 2; h++) {
#pragma unroll
      for (int ni = 0; ni < 4; ni++) {
        float4 b4 = *(const float4*)(bias + colBlk + wc * 64 + ni * 16 + g * 4);
#pragma unroll
        for (int mi2 = 0; mi2 < 4; mi2++) {
          int mi = h * 4 + mi2;
          float v0 = acc[mi][ni][0] + b4.x, v1 = acc[mi][ni][1] + b4.y,
                v2 = acc[mi][ni][2] + b4.z, v3 = acc[mi][ni][3] + b4.w;
          if constexpr (EPI == EPI_FF1) {
            v0 = gelu_fast(v0); v1 = gelu_fast(v1);
            v2 = gelu_fast(v2); v3 = gelu_fast(v3);
          }
          short4v s4 = {(short)__bfloat16_as_ushort(__float2bfloat16(v0)),
                        (short)__bfloat16_as_ushort(__float2bfloat16(v1)),
                        (short)__bfloat16_as_ushort(__float2bfloat16(v2)),
                        (short)__bfloat16_as_ushort(__float2bfloat16(v3))};
          int row = mi2 * 16 + r16;
          int ch8 = (ni * 2 + (g >> 1)) ^ (row & 7);
          *(short4v*)(&EP[row * 64 + ch8 * 8 + (g & 1) * 4]) = s4;
        }
      }
#pragma unroll
      for (int j = 0; j < 8; j++) {
        int r = j * 8 + (lane >> 3);
        bf16x8 vv = *(const bf16x8*)(&EP[r * 64 + ((lane & 7) ^ (r & 7)) * 8]);
        int grow = rowBlk + wr * 128 + h * 64 + r;
        int col0 = colBlk + wc * 64 + (lane & 7) * 8;
        if constexpr (EPI == EPI_QKV) {
          int winr = grow / 49, nn = grow - winr * 49;
          int which = col0 / 384; int rem = col0 - which * 384;
          int hh = rem >> 5, dd = rem & 31;
          size_t off = (((size_t)winr * 12 + hh) * 49 + nn) * 32 + dd;
          *(bf16x8*)(out_b + (size_t)which * 38535168u + off) = vv;
        } else {
          *(bf16x8*)(out_b + (size_t)grow * 1536 + col0) = vv;
        }
      }
    }
  } else {
    float* EPF = (float*)LB + w * 2048;   // 32x64 f32, four quarter-passes
#pragma unroll
    for (int q2 = 0; q2 < 4; q2++) {
#pragma unroll
      for (int ni = 0; ni < 4; ni++) {
        float4 b4 = *(const float4*)(bias + colBlk + wc * 64 + ni * 16 + g * 4);
#pragma unroll
        for (int mi2 = 0; mi2 < 2; mi2++) {
          int mi = q2 * 2 + mi2;
          f32x4 v = acc[mi][ni];
          v[0] += b4.x; v[1] += b4.y; v[2] += b4.z; v[3] += b4.w;
          int row = mi2 * 16 + r16;
          int ch4 = (ni * 4 + g) ^ r16;
          *(f32x4*)(&EPF[row * 64 + ch4 * 4]) = v;
        }
      }
#pragma unroll
      for (int j = 0; j < 8; j++) {
        int r = j * 4 + g;
        f32x4 vv = *(const f32x4*)(&EPF[r * 64 + ((r16 ^ (r & 15)) * 4)]);
        int grow = rowBlk + wr * 128 + q2 * 32 + r;
        int col0 = colBlk + wc * 64 + r16 * 4;
        if constexpr (EPI == EPI_PROJ) {
          size_t nt2 = win_to_nat(grow);
          const float4 a4 = *(const float4*)(aux + nt2 * 384 + col0);
          float4 o4 = {vv[0] + a4.x, vv[1] + a4.y, vv[2] + a4.z, vv[3] + a4.w};
          *(float4*)(out_f + nt2 * 384 + col0) = o4;
        } else {
          const float4 a4 = *(const float4*)(aux + (size_t)grow * 384 + col0);
          float4 o4 = {vv[0] + a4.x, vv[1] + a4.y, vv[2] + a4.z, vv[3] + a4.w};
          *(float4*)(out_f + (size_t)grow * 384 + col0) = o4;
        }
      }
    }
  }
}

// ---------- windowed attention: 1 wave per (window, head) ----------
__global__ __launch_bounds__(256)
void k_attn(const __hip_bfloat16* __restrict__ q, const __hip_bfloat16* __restrict__ k,
            const __hip_bfloat16* __restrict__ v, const float* __restrict__ rpb,
            __hip_bfloat16* __restrict__ o) {
  __shared__ __hip_bfloat16 P[4][64][72];
  int tid = threadIdx.x;
  int lane = tid & 63, wave = tid >> 6;
  int g = lane >> 4, r16 = lane & 15;
  int gid = blockIdx.x * 4 + wave;
  int wi = gid / 12, h = gid - (gid / 12) * 12;
  int wimg = wi & 63;
  int hb = wimg >> 3, wb = wimg & 7;
  size_t base = ((size_t)wi * 12 + h) * (49 * 32);
  const __hip_bfloat16* qb = q + base;
  const __hip_bfloat16* kb = k + base;
  const __hip_bfloat16* vb = v + base;

  bf16x8 zf = {0, 0, 0, 0, 0, 0, 0, 0};
  bf16x8 qf[4], kf[4];
#pragma unroll
  for (int mi = 0; mi < 4; mi++) {
    int row = mi * 16 + r16;
    qf[mi] = (row < 49) ? *(const bf16x8*)(qb + row * 32 + g * 8) : zf;
    kf[mi] = (row < 49) ? *(const bf16x8*)(kb + row * 32 + g * 8) : zf;
  }
  f32x4 fz = {0.f, 0.f, 0.f, 0.f};
  f32x4 S[4][4];
#pragma unroll
  for (int mi = 0; mi < 4; mi++)
#pragma unroll
    for (int ni = 0; ni < 4; ni++)
      S[mi][ni] = __builtin_amdgcn_mfma_f32_16x16x32_bf16(qf[mi], kf[ni], fz, 0, 0, 0);

  int kiA[4], kjA[4], rkA[4], cvA[4];
#pragma unroll
  for (int ni = 0; ni < 4; ni++) {
    int col = ni * 16 + r16;
    cvA[ni] = (col < 49);
    int ki = col / 7, kj = col - (col / 7) * 7;
    kiA[ni] = ki; kjA[ni] = kj;
    int hg = hb * 7 + ki, wg = wb * 7 + kj;
    int rh = (hg < 49) ? 0 : ((hg < 53) ? 1 : 2);
    int rw = (wg < 49) ? 0 : ((wg < 53) ? 1 : 2);
    rkA[ni] = rh * 3 + rw;
  }

#pragma unroll
  for (int mi = 0; mi < 4; mi++) {
#pragma unroll
    for (int rr = 0; rr < 4; rr++) {
      int row = mi * 16 + g * 4 + rr;
      float sv[4];
      float mx = -1e30f;
      int qi = row / 7, qj = row - (row / 7) * 7;
      int hgq = hb * 7 + qi, wgq = wb * 7 + qj;
      int rhq = (hgq < 49) ? 0 : ((hgq < 53) ? 1 : 2);
      int rwq = (wgq < 49) ? 0 : ((wgq < 53) ? 1 : 2);
      int rq = rhq * 3 + rwq;
#pragma unroll
      for (int ni = 0; ni < 4; ni++) {
        float s = -1e30f;
        if (row < 49 && cvA[ni]) {
          int idx = (qi - kiA[ni] + 6) * 13 + (qj - kjA[ni] + 6);
          float maskv = (rq != rkA[ni]) ? -100.f : 0.f;
          s = S[mi][ni][rr] * SCALE + rpb[idx * 12 + h] + maskv;
        }
        sv[ni] = s;
        mx = fmaxf(mx, s);
      }
#pragma unroll
      for (int m = 1; m <= 8; m <<= 1) mx = fmaxf(mx, __shfl_xor(mx, m));
      float sum = 0.f;
#pragma unroll
      for (int ni = 0; ni < 4; ni++) {
        float p = __expf(sv[ni] - mx);
        sv[ni] = p; sum += p;
      }
#pragma unroll
      for (int m = 1; m <= 8; m <<= 1) sum += __shfl_xor(sum, m);
      float inv = 1.f / sum;
#pragma unroll
      for (int ni = 0; ni < 4; ni++)
        P[wave][row][ni * 16 + r16] = __float2bfloat16(sv[ni] * inv);
    }
  }

  f32x4 O[4][2] = {};
#pragma unroll
  for (int ks = 0; ks < 2; ks++) {
    bf16x8 pf[4];
#pragma unroll
    for (int mi = 0; mi < 4; mi++)
      pf[mi] = *(const bf16x8*)(&P[wave][mi * 16 + r16][ks * 32 + g * 8]);
#pragma unroll
    for (int ni = 0; ni < 2; ni++) {
      bf16x8 vf = zf;
#pragma unroll
      for (int j = 0; j < 8; j++) {
        int m = ks * 32 + g * 8 + j;
        if (m < 49) vf[j] = ((const short*)vb)[m * 32 + ni * 16 + r16];
      }
#pragma unroll
      for (int mi = 0; mi < 4; mi++)
        O[mi][ni] = __builtin_amdgcn_mfma_f32_16x16x32_bf16(pf[mi], vf, O[mi][ni], 0, 0, 0);
    }
  }

#pragma unroll
  for (int mi = 0; mi < 4; mi++)
#pragma unroll
    for (int rr = 0; rr < 4; rr++) {
      int row = mi * 16 + g * 4 + rr;
      if (row < 49) {
#pragma unroll
        for (int ni = 0; ni < 2; ni++) {
          int col = ni * 16 + r16;
          o[(((size_t)wi * 49 + row) * 12 + h) * 32 + col] = __float2bfloat16(O[mi][ni][rr]);
        }
      }
    }
}

// ---------- host launch ----------
extern "C" void kernel_launch(void* const* d_in, const int* in_sizes, int n_in,
                              void* d_out, int out_size, void* d_ws, size_t ws_size,
                              hipStream_t stream) {
  const float* x      = (const float*)d_in[0];
  const float* ln1_g  = (const float*)d_in[1];
  const float* ln1_b  = (const float*)d_in[2];
  const float* qkv_w  = (const float*)d_in[3];
  const float* qkv_b  = (const float*)d_in[4];
  const float* proj_w = (const float*)d_in[5];
  const float* proj_b = (const float*)d_in[6];
  const float* rpb    = (const float*)d_in[7];
  const float* ln2_g  = (const float*)d_in[8];
  const float* ln2_b  = (const float*)d_in[9];
  const float* ffg    = (const float*)d_in[10];
  const float* ffb    = (const float*)d_in[11];
  const float* ff1_w  = (const float*)d_in[12];
  const float* ff1_b  = (const float*)d_in[13];
  const float* ff2_w  = (const float*)d_in[14];
  const float* ff2_b  = (const float*)d_in[15];
  float* out = (float*)d_out;

  char* ws = (char*)d_ws;
  __hip_bfloat16* xw     = (__hip_bfloat16*)ws;
  __hip_bfloat16* qbuf   = (__hip_bfloat16*)(ws + 77070336u);
  __hip_bfloat16* kbuf   = qbuf + 38535168u;
  __hip_bfloat16* vbuf   = kbuf + 38535168u;
  __hip_bfloat16* attn_o = xw;
  __hip_bfloat16* hbuf   = (__hip_bfloat16*)ws;
  float*          x_res  = (float*)(ws + 308281344u);
  __hip_bfloat16* yln    = (__hip_bfloat16*)(ws + 462422016u);
  __hip_bfloat16* qkv_wt = (__hip_bfloat16*)(ws + 539492352u);
  __hip_bfloat16* proj_wt = qkv_wt + 442368u;
  __hip_bfloat16* ff1_wt  = proj_wt + 147456u;
  __hip_bfloat16* ff2_wt  = ff1_wt + 589824u;

  // weight prep
  k_transpose<<<dim3(1152 / 32, 384 / 32), dim3(256), 0, stream>>>(qkv_w, qkv_wt, 384, 1152);
  k_transpose<<<dim3(384 / 32, 384 / 32), dim3(256), 0, stream>>>(proj_w, proj_wt, 384, 384);
  k_transpose<<<dim3(1536 / 32, 384 / 32), dim3(256), 0, stream>>>(ff1_w, ff1_wt, 384, 1536);
  k_transpose<<<dim3(384 / 32, 1536 / 32), dim3(256), 0, stream>>>(ff2_w, ff2_wt, 1536, 384);

  // LN1 + shift + window partition
  k_ln1<<<dim3(25088), dim3(256), 0, stream>>>(x, ln1_g, ln1_b, xw);

  // GEMMs: 512x128 tiles. M blocks = 100352/512 = 196.
  // QKV: nCol = 9 -> nwg 1764
  k_gemm<EPI_QKV><<<dim3(1764), dim3(512), 0, stream>>>(xw, qkv_wt, qkv_b, 384, 9, 1764,
                                                        nullptr, nullptr, qbuf);
  // attention
  k_attn<<<dim3(6144), dim3(256), 0, stream>>>(qbuf, kbuf, vbuf, rpb, attn_o);
  // proj: nCol = 3 -> nwg 588
  k_gemm<EPI_PROJ><<<dim3(588), dim3(512), 0, stream>>>(attn_o, proj_wt, proj_b, 384, 3, 588,
                                                        x, x_res, nullptr);
  // LN2 + ffLN
  k_ln2ff<<<dim3(25088), dim3(256), 0, stream>>>(x_res, ln2_g, ln2_b, ffg, ffb, yln);
  // FF1 + gelu: nCol = 12 -> nwg 2352
  k_gemm<EPI_FF1><<<dim3(2352), dim3(512), 0, stream>>>(yln, ff1_wt, ff1_b, 384, 12, 2352,
                                                        nullptr, nullptr, hbuf);
  // FF2 + residual: K=1536, nCol = 3 -> nwg 588
  k_gemm<EPI_FF2><<<dim3(588), dim3(512), 0, stream>>>(hbuf, ff2_wt, ff2_b, 1536, 3, 588,
                                                       x_res, out, nullptr);
}

// Round 16
// 872.806 us; speedup vs baseline: 1.3955x; 1.1012x over previous
//
#include <hip/hip_runtime.h>
#include <hip/hip_bf16.h>

typedef short bf16x8 __attribute__((ext_vector_type(8)));
typedef short short4v __attribute__((ext_vector_type(4)));
typedef float f32x4  __attribute__((ext_vector_type(4)));

// ---------- problem constants ----------
static constexpr float SCALE = 0.17677669529663687f; // 32^-0.5

__device__ __forceinline__ void gload_lds16(const void* g, void* l) {
  __builtin_amdgcn_global_load_lds(
      (const __attribute__((address_space(1))) unsigned int*)g,
      (__attribute__((address_space(3))) unsigned int*)l, 16, 0, 0);
}

__device__ __forceinline__ size_t win_to_nat(int t) {
  int win = t / 49; int n = t - win * 49;
  int bb = win >> 6; int wimg = win & 63;
  int hb = wimg >> 3, wb = wimg & 7;
  int nr = n / 7, nc = n - nr * 7;
  int hh = hb * 7 + nr + 3; if (hh >= 56) hh -= 56;
  int ww = wb * 7 + nc + 3; if (ww >= 56) ww -= 56;
  return (size_t)bb * 3136 + (size_t)hh * 56 + ww;
}

__device__ __forceinline__ float gelu_fast(float x) {
  float t = __expf(-1.702f * x);
  return x / (1.f + t);
}

__device__ __forceinline__ float b2f(short s) {
  unsigned int u = ((unsigned int)(unsigned short)s) << 16;
  return __uint_as_float(u);
}
__device__ __forceinline__ short f2b(float f) {
  return (short)__bfloat16_as_ushort(__float2bfloat16(f));
}

// ---------- LDS-tiled weight transpose+cast ----------
__global__ __launch_bounds__(256)
void k_transpose(const float* __restrict__ W, __hip_bfloat16* __restrict__ Wt,
                 int K, int N) {
  __shared__ float tile[32][33];
  int tx = threadIdx.x & 31, ty = threadIdx.x >> 5;
  int tc = blockIdx.x, tr = blockIdx.y;
#pragma unroll
  for (int r = 0; r < 32; r += 8)
    tile[r + ty][tx] = W[(size_t)(tr * 32 + r + ty) * N + tc * 32 + tx];
  __syncthreads();
#pragma unroll
  for (int r = 0; r < 32; r += 8)
    Wt[(size_t)(tc * 32 + r + ty) * K + tr * 32 + tx] =
        __float2bfloat16(tile[tx][r + ty]);
}

// ---------- LN1 + roll + window partition ----------
__global__ __launch_bounds__(256)
void k_ln1(const float* __restrict__ x, const float* __restrict__ gw,
           const float* __restrict__ bw, __hip_bfloat16* __restrict__ xw) {
  int lane = threadIdx.x & 63;
  int t = blockIdx.x * 4 + (threadIdx.x >> 6);
  size_t nt = win_to_nat(t);
  const float* xr = x + nt * 384;
  float4 a  = *(const float4*)(xr + lane * 4);
  float2 c2 = *(const float2*)(xr + 256 + lane * 2);
  float v[6] = {a.x, a.y, a.z, a.w, c2.x, c2.y};
  int c0 = lane * 4, c1 = 256 + lane * 2;
  int ch[6] = {c0, c0 + 1, c0 + 2, c0 + 3, c1, c1 + 1};
  float s = 0.f, q = 0.f;
#pragma unroll
  for (int i = 0; i < 6; i++) { s += v[i]; q += v[i] * v[i]; }
#pragma unroll
  for (int m = 1; m < 64; m <<= 1) { s += __shfl_xor(s, m); q += __shfl_xor(q, m); }
  float mean = s * (1.f / 384.f);
  float rstd = rsqrtf(q * (1.f / 384.f) - mean * mean + 1e-5f);
  __hip_bfloat16* o = xw + (size_t)t * 384;
#pragma unroll
  for (int i = 0; i < 6; i++)
    o[ch[i]] = __float2bfloat16((v[i] - mean) * rstd * gw[ch[i]] + bw[ch[i]]);
}

// ---------- double LN (reads bf16 x_res) ----------
__global__ __launch_bounds__(256)
void k_ln2ff(const __hip_bfloat16* __restrict__ xres, const float* __restrict__ g2,
             const float* __restrict__ b2, const float* __restrict__ gf,
             const float* __restrict__ bf_, __hip_bfloat16* __restrict__ yln) {
  int lane = threadIdx.x & 63;
  int t = blockIdx.x * 4 + (threadIdx.x >> 6);
  const __hip_bfloat16* xr = xres + (size_t)t * 384;
  short4v a = *(const short4v*)(xr + lane * 4);
  int c2 = *(const int*)(xr + 256 + lane * 2);
  float v[6] = {b2f(a[0]), b2f(a[1]), b2f(a[2]), b2f(a[3]),
                b2f((short)(c2 & 0xffff)), b2f((short)((unsigned)c2 >> 16))};
  int c0 = lane * 4, c1 = 256 + lane * 2;
  int ch[6] = {c0, c0 + 1, c0 + 2, c0 + 3, c1, c1 + 1};
  float s = 0.f, q = 0.f;
#pragma unroll
  for (int i = 0; i < 6; i++) { s += v[i]; q += v[i] * v[i]; }
#pragma unroll
  for (int m = 1; m < 64; m <<= 1) { s += __shfl_xor(s, m); q += __shfl_xor(q, m); }
  float mean = s * (1.f / 384.f);
  float rstd = rsqrtf(q * (1.f / 384.f) - mean * mean + 1e-5f);
  float y1[6];
  s = 0.f; q = 0.f;
#pragma unroll
  for (int i = 0; i < 6; i++) {
    y1[i] = (v[i] - mean) * rstd * g2[ch[i]] + b2[ch[i]];
    s += y1[i]; q += y1[i] * y1[i];
  }
#pragma unroll
  for (int m = 1; m < 64; m <<= 1) { s += __shfl_xor(s, m); q += __shfl_xor(q, m); }
  float m2 = s * (1.f / 384.f);
  float r2 = rsqrtf(q * (1.f / 384.f) - m2 * m2 + 1e-6f);
  __hip_bfloat16* o = yln + (size_t)t * 384;
#pragma unroll
  for (int i = 0; i < 6; i++)
    o[ch[i]] = __float2bfloat16((y1[i] - m2) * r2 * gf[ch[i]] + bf_[ch[i]]);
}

// ---------- R11 GEMM (best measured): depth-2 prefetch, 3-buffer, 2-barrier ----
// 128x128 tile, BK=32, 4 waves (2x2), 48KB LDS. STEP: STG(t+2) -> vmcnt(8) ->
// barrier(publish) -> ds_reads -> MFMA -> barrier(reads retired).
// R11 line-pair LDS map (conflict-free). Operand-swapped MFMA.
// x_res is now bf16: PROJ writes out_b (bf16), FF2 reads auxb (bf16).
enum { EPI_QKV = 0, EPI_PROJ = 1, EPI_FF1 = 2, EPI_FF2 = 3 };

template <int EPI>
__global__ __launch_bounds__(256)
void k_gemm(const __hip_bfloat16* __restrict__ A, const __hip_bfloat16* __restrict__ Wt,
            const float* __restrict__ bias, int K, int nCol, int cpx,
            const float* __restrict__ aux,        // PROJ: x (f32)
            const __hip_bfloat16* __restrict__ auxb, // FF2: x_res (bf16)
            float* __restrict__ out_f,            // FF2: final out
            __hip_bfloat16* __restrict__ out_b) { // QKV: q; FF1: hbuf; PROJ: x_res
  __shared__ __hip_bfloat16 LB[24576];   // 48KB: A bufs [0,12288), B bufs [12288,24576)
  int tid = threadIdx.x;
  int lane = tid & 63, w = tid >> 6;
  int g = lane >> 4, r16 = lane & 15;
  int wr = w >> 1, wc = w & 1;

  int bid = blockIdx.x;
  int wg = (bid & 7) * cpx + (bid >> 3);   // XCD swizzle (nwg % 8 == 0)
  int rB = wg / nCol;
  int rowBlk = rB * 128;
  int colBlk = (wg - rB * nCol) * 128;

  int s2 = (tid & 7) ^ ((tid >> 3) & 7);
  int srow = 2 * (tid >> 3) + (s2 >> 2);
  int cch = s2 & 3;
  const __hip_bfloat16* PA = A + (size_t)(rowBlk + srow) * K + cch * 8;
  const __hip_bfloat16* PB = Wt + (size_t)(colBlk + srow) * K + cch * 8;

#define STG(NB, T)                                                            \
  {                                                                           \
    int k0s = (T) << 5;                                                       \
    _Pragma("unroll") for (int j = 0; j < 2; j++) {                           \
      gload_lds16(PA + (size_t)j * 64 * K + k0s, &LB[(NB) * 4096 + j * 2048 + w * 512]); \
      gload_lds16(PB + (size_t)j * 64 * K + k0s, &LB[12288 + (NB) * 4096 + j * 2048 + w * 512]); \
    }                                                                         \
  }

  int rslot = (g + ((r16 & 1) << 2)) ^ (r16 >> 1);
  int aBase = (wr * 32 + (r16 >> 1)) * 64 + rslot * 8;
  int bBase = 12288 + (wc * 32 + (r16 >> 1)) * 64 + rslot * 8;

  f32x4 acc[4][4] = {};
  const int nt = K >> 5;   // 12 or 48

  STG(0, 0)
  STG(1, 1)

#define STEP(CB, SB, T)                                                       \
  {                                                                           \
    if ((T) + 2 < nt) {                                                       \
      STG(SB, (T) + 2)                                                        \
      asm volatile("s_waitcnt vmcnt(8)" ::: "memory");                        \
    } else if ((T) + 1 < nt) {                                                \
      asm volatile("s_waitcnt vmcnt(4)" ::: "memory");                        \
    } else {                                                                  \
      asm volatile("s_waitcnt vmcnt(0)" ::: "memory");                        \
    }                                                                         \
    __builtin_amdgcn_s_barrier();                                             \
    bf16x8 a[4], b[4];                                                        \
    _Pragma("unroll") for (int mi = 0; mi < 4; mi++)                          \
      a[mi] = *(const bf16x8*)(&LB[(CB) * 4096 + aBase + mi * 512]);          \
    _Pragma("unroll") for (int ni = 0; ni < 4; ni++)                          \
      b[ni] = *(const bf16x8*)(&LB[(CB) * 4096 + bBase + ni * 512]);          \
    __builtin_amdgcn_s_setprio(1);                                            \
    _Pragma("unroll") for (int mi = 0; mi < 4; mi++)                          \
      _Pragma("unroll") for (int ni = 0; ni < 4; ni++)                        \
        acc[mi][ni] = __builtin_amdgcn_mfma_f32_16x16x32_bf16(                \
            b[ni], a[mi], acc[mi][ni], 0, 0, 0);                              \
    __builtin_amdgcn_s_setprio(0);                                            \
    __builtin_amdgcn_s_barrier();                                             \
  }

  for (int t = 0; t < nt; t += 3) {
    STEP(0, 2, t)
    STEP(1, 0, t + 1)
    STEP(2, 1, t + 2)
  }
#undef STEP
#undef STG

  // ---- vectorized epilogue via per-wave LDS tiles ----
  if constexpr (EPI == EPI_QKV || EPI == EPI_FF1) {
    __hip_bfloat16* EP = &LB[w * 4096];   // 64x64 bf16/wave
#pragma unroll
    for (int ni = 0; ni < 4; ni++) {
      float4 b4 = *(const float4*)(bias + colBlk + wc * 64 + ni * 16 + g * 4);
#pragma unroll
      for (int mi = 0; mi < 4; mi++) {
        float v0 = acc[mi][ni][0] + b4.x, v1 = acc[mi][ni][1] + b4.y,
              v2 = acc[mi][ni][2] + b4.z, v3 = acc[mi][ni][3] + b4.w;
        if constexpr (EPI == EPI_FF1) {
          v0 = gelu_fast(v0); v1 = gelu_fast(v1);
          v2 = gelu_fast(v2); v3 = gelu_fast(v3);
        }
        short4v s4 = {f2b(v0), f2b(v1), f2b(v2), f2b(v3)};
        int row = mi * 16 + r16;
        int ch8 = (ni * 2 + (g >> 1)) ^ (row & 7);
        *(short4v*)(&EP[row * 64 + ch8 * 8 + (g & 1) * 4]) = s4;
      }
    }
#pragma unroll
    for (int j = 0; j < 8; j++) {
      int r = j * 8 + (lane >> 3);
      bf16x8 vv = *(const bf16x8*)(&EP[r * 64 + ((lane & 7) ^ (r & 7)) * 8]);
      int grow = rowBlk + wr * 64 + r;
      int col0 = colBlk + wc * 64 + (lane & 7) * 8;
      if constexpr (EPI == EPI_QKV) {
        int winr = grow / 49, nn = grow - winr * 49;
        int which = col0 / 384; int rem = col0 - which * 384;
        int hh = rem >> 5, dd = rem & 31;
        size_t off = (((size_t)winr * 12 + hh) * 49 + nn) * 32 + dd;
        *(bf16x8*)(out_b + (size_t)which * 38535168u + off) = vv;
      } else {
        *(bf16x8*)(out_b + (size_t)grow * 1536 + col0) = vv;
      }
    }
  } else {
    float* EPF = (float*)LB + w * 2048;   // 32x64 f32/wave, 2 half-passes
#pragma unroll
    for (int half = 0; half < 2; half++) {
#pragma unroll
      for (int ni = 0; ni < 4; ni++) {
        float4 b4 = *(const float4*)(bias + colBlk + wc * 64 + ni * 16 + g * 4);
#pragma unroll
        for (int mi2 = 0; mi2 < 2; mi2++) {
          int mi = half * 2 + mi2;
          f32x4 v = acc[mi][ni];
          v[0] += b4.x; v[1] += b4.y; v[2] += b4.z; v[3] += b4.w;
          int row = mi2 * 16 + r16;
          int ch4 = (ni * 4 + g) ^ r16;
          *(f32x4*)(&EPF[row * 64 + ch4 * 4]) = v;
        }
      }
#pragma unroll
      for (int j = 0; j < 8; j++) {
        int r = j * 4 + g;
        f32x4 vv = *(const f32x4*)(&EPF[r * 64 + ((r16 ^ (r & 15)) * 4)]);
        int grow = rowBlk + wr * 64 + half * 32 + r;
        int col0 = colBlk + wc * 64 + r16 * 4;
        if constexpr (EPI == EPI_PROJ) {
          // x_res (bf16) = proj + x (f32 input residual)
          size_t nt2 = win_to_nat(grow);
          const float4 a4 = *(const float4*)(aux + nt2 * 384 + col0);
          short4v s4 = {f2b(vv[0] + a4.x), f2b(vv[1] + a4.y),
                        f2b(vv[2] + a4.z), f2b(vv[3] + a4.w)};
          *(short4v*)(out_b + nt2 * 384 + col0) = s4;
        } else {
          // final out (f32) = ff2 + x_res (bf16)
          short4v a4 = *(const short4v*)(auxb + (size_t)grow * 384 + col0);
          float4 o4 = {vv[0] + b2f(a4[0]), vv[1] + b2f(a4[1]),
                       vv[2] + b2f(a4[2]), vv[3] + b2f(a4[3])};
          *(float4*)(out_f + (size_t)grow * 384 + col0) = o4;
        }
      }
    }
  }
}

// ---------- windowed attention: 1 wave per (window, head) ----------
__global__ __launch_bounds__(256)
void k_attn(const __hip_bfloat16* __restrict__ q, const __hip_bfloat16* __restrict__ k,
            const __hip_bfloat16* __restrict__ v, const float* __restrict__ rpb,
            __hip_bfloat16* __restrict__ o) {
  __shared__ __hip_bfloat16 P[4][64][72];
  int tid = threadIdx.x;
  int lane = tid & 63, wave = tid >> 6;
  int g = lane >> 4, r16 = lane & 15;
  int gid = blockIdx.x * 4 + wave;
  int wi = gid / 12, h = gid - (gid / 12) * 12;
  int wimg = wi & 63;
  int hb = wimg >> 3, wb = wimg & 7;
  size_t base = ((size_t)wi * 12 + h) * (49 * 32);
  const __hip_bfloat16* qb = q + base;
  const __hip_bfloat16* kb = k + base;
  const __hip_bfloat16* vb = v + base;

  bf16x8 zf = {0, 0, 0, 0, 0, 0, 0, 0};
  bf16x8 qf[4], kf[4];
#pragma unroll
  for (int mi = 0; mi < 4; mi++) {
    int row = mi * 16 + r16;
    qf[mi] = (row < 49) ? *(const bf16x8*)(qb + row * 32 + g * 8) : zf;
    kf[mi] = (row < 49) ? *(const bf16x8*)(kb + row * 32 + g * 8) : zf;
  }
  f32x4 fz = {0.f, 0.f, 0.f, 0.f};
  f32x4 S[4][4];
#pragma unroll
  for (int mi = 0; mi < 4; mi++)
#pragma unroll
    for (int ni = 0; ni < 4; ni++)
      S[mi][ni] = __builtin_amdgcn_mfma_f32_16x16x32_bf16(qf[mi], kf[ni], fz, 0, 0, 0);

  int kiA[4], kjA[4], rkA[4], cvA[4];
#pragma unroll
  for (int ni = 0; ni < 4; ni++) {
    int col = ni * 16 + r16;
    cvA[ni] = (col < 49);
    int ki = col / 7, kj = col - (col / 7) * 7;
    kiA[ni] = ki; kjA[ni] = kj;
    int hg = hb * 7 + ki, wg = wb * 7 + kj;
    int rh = (hg < 49) ? 0 : ((hg < 53) ? 1 : 2);
    int rw = (wg < 49) ? 0 : ((wg < 53) ? 1 : 2);
    rkA[ni] = rh * 3 + rw;
  }

#pragma unroll
  for (int mi = 0; mi < 4; mi++) {
#pragma unroll
    for (int rr = 0; rr < 4; rr++) {
      int row = mi * 16 + g * 4 + rr;
      float sv[4];
      float mx = -1e30f;
      int qi = row / 7, qj = row - (row / 7) * 7;
      int hgq = hb * 7 + qi, wgq = wb * 7 + qj;
      int rhq = (hgq < 49) ? 0 : ((hgq < 53) ? 1 : 2);
      int rwq = (wgq < 49) ? 0 : ((wgq < 53) ? 1 : 2);
      int rq = rhq * 3 + rwq;
#pragma unroll
      for (int ni = 0; ni < 4; ni++) {
        float s = -1e30f;
        if (row < 49 && cvA[ni]) {
          int idx = (qi - kiA[ni] + 6) * 13 + (qj - kjA[ni] + 6);
          float maskv = (rq != rkA[ni]) ? -100.f : 0.f;
          s = S[mi][ni][rr] * SCALE + rpb[idx * 12 + h] + maskv;
        }
        sv[ni] = s;
        mx = fmaxf(mx, s);
      }
#pragma unroll
      for (int m = 1; m <= 8; m <<= 1) mx = fmaxf(mx, __shfl_xor(mx, m));
      float sum = 0.f;
#pragma unroll
      for (int ni = 0; ni < 4; ni++) {
        float p = __expf(sv[ni] - mx);
        sv[ni] = p; sum += p;
      }
#pragma unroll
      for (int m = 1; m <= 8; m <<= 1) sum += __shfl_xor(sum, m);
      float inv = 1.f / sum;
#pragma unroll
      for (int ni = 0; ni < 4; ni++)
        P[wave][row][ni * 16 + r16] = __float2bfloat16(sv[ni] * inv);
    }
  }

  f32x4 O[4][2] = {};
#pragma unroll
  for (int ks = 0; ks < 2; ks++) {
    bf16x8 pf[4];
#pragma unroll
    for (int mi = 0; mi < 4; mi++)
      pf[mi] = *(const bf16x8*)(&P[wave][mi * 16 + r16][ks * 32 + g * 8]);
#pragma unroll
    for (int ni = 0; ni < 2; ni++) {
      bf16x8 vf = zf;
#pragma unroll
      for (int j = 0; j < 8; j++) {
        int m = ks * 32 + g * 8 + j;
        if (m < 49) vf[j] = ((const short*)vb)[m * 32 + ni * 16 + r16];
      }
#pragma unroll
      for (int mi = 0; mi < 4; mi++)
        O[mi][ni] = __builtin_amdgcn_mfma_f32_16x16x32_bf16(pf[mi], vf, O[mi][ni], 0, 0, 0);
    }
  }

#pragma unroll
  for (int mi = 0; mi < 4; mi++)
#pragma unroll
    for (int rr = 0; rr < 4; rr++) {
      int row = mi * 16 + g * 4 + rr;
      if (row < 49) {
#pragma unroll
        for (int ni = 0; ni < 2; ni++) {
          int col = ni * 16 + r16;
          o[(((size_t)wi * 49 + row) * 12 + h) * 32 + col] = __float2bfloat16(O[mi][ni][rr]);
        }
      }
    }
}

// ---------- host launch ----------
extern "C" void kernel_launch(void* const* d_in, const int* in_sizes, int n_in,
                              void* d_out, int out_size, void* d_ws, size_t ws_size,
                              hipStream_t stream) {
  const float* x      = (const float*)d_in[0];
  const float* ln1_g  = (const float*)d_in[1];
  const float* ln1_b  = (const float*)d_in[2];
  const float* qkv_w  = (const float*)d_in[3];
  const float* qkv_b  = (const float*)d_in[4];
  const float* proj_w = (const float*)d_in[5];
  const float* proj_b = (const float*)d_in[6];
  const float* rpb    = (const float*)d_in[7];
  const float* ln2_g  = (const float*)d_in[8];
  const float* ln2_b  = (const float*)d_in[9];
  const float* ffg    = (const float*)d_in[10];
  const float* ffb    = (const float*)d_in[11];
  const float* ff1_w  = (const float*)d_in[12];
  const float* ff1_b  = (const float*)d_in[13];
  const float* ff2_w  = (const float*)d_in[14];
  const float* ff2_b  = (const float*)d_in[15];
  float* out = (float*)d_out;

  char* ws = (char*)d_ws;
  __hip_bfloat16* xw     = (__hip_bfloat16*)ws;
  __hip_bfloat16* qbuf   = (__hip_bfloat16*)(ws + 77070336u);
  __hip_bfloat16* kbuf   = qbuf + 38535168u;
  __hip_bfloat16* vbuf   = kbuf + 38535168u;
  __hip_bfloat16* attn_o = xw;
  __hip_bfloat16* hbuf   = (__hip_bfloat16*)ws;
  __hip_bfloat16* x_res  = (__hip_bfloat16*)(ws + 308281344u);   // bf16 now
  __hip_bfloat16* yln    = (__hip_bfloat16*)(ws + 462422016u);
  __hip_bfloat16* qkv_wt = (__hip_bfloat16*)(ws + 539492352u);
  __hip_bfloat16* proj_wt = qkv_wt + 442368u;
  __hip_bfloat16* ff1_wt  = proj_wt + 147456u;
  __hip_bfloat16* ff2_wt  = ff1_wt + 589824u;

  // weight prep
  k_transpose<<<dim3(1152 / 32, 384 / 32), dim3(256), 0, stream>>>(qkv_w, qkv_wt, 384, 1152);
  k_transpose<<<dim3(384 / 32, 384 / 32), dim3(256), 0, stream>>>(proj_w, proj_wt, 384, 384);
  k_transpose<<<dim3(1536 / 32, 384 / 32), dim3(256), 0, stream>>>(ff1_w, ff1_wt, 384, 1536);
  k_transpose<<<dim3(384 / 32, 1536 / 32), dim3(256), 0, stream>>>(ff2_w, ff2_wt, 1536, 384);

  // LN1 + shift + window partition
  k_ln1<<<dim3(25088), dim3(256), 0, stream>>>(x, ln1_g, ln1_b, xw);

  // GEMMs: 128x128 tiles. M blocks = 784.
  k_gemm<EPI_QKV><<<dim3(7056), dim3(256), 0, stream>>>(xw, qkv_wt, qkv_b, 384, 9, 7056 / 8,
                                                        nullptr, nullptr, nullptr, qbuf);
  // attention
  k_attn<<<dim3(6144), dim3(256), 0, stream>>>(qbuf, kbuf, vbuf, rpb, attn_o);
  // proj + window reverse + residual -> x_res (bf16)
  k_gemm<EPI_PROJ><<<dim3(2352), dim3(256), 0, stream>>>(attn_o, proj_wt, proj_b, 384, 3, 2352 / 8,
                                                         x, nullptr, nullptr, x_res);
  // LN2 + ffLN (bf16 in)
  k_ln2ff<<<dim3(25088), dim3(256), 0, stream>>>(x_res, ln2_g, ln2_b, ffg, ffb, yln);
  // FF1 + gelu
  k_gemm<EPI_FF1><<<dim3(9408), dim3(256), 0, stream>>>(yln, ff1_wt, ff1_b, 384, 12, 9408 / 8,
                                                        nullptr, nullptr, nullptr, hbuf);
  // FF2 + residual (bf16 aux) -> out (f32)
  k_gemm<EPI_FF2><<<dim3(2352), dim3(256), 0, stream>>>(hbuf, ff2_wt, ff2_b, 1536, 3, 2352 / 8,
                                                        nullptr, x_res, out, nullptr);
}

// Round 17
// 864.004 us; speedup vs baseline: 1.4098x; 1.0102x over previous
//
#include <hip/hip_runtime.h>
#include <hip/hip_bf16.h>

typedef short bf16x8 __attribute__((ext_vector_type(8)));
typedef short short4v __attribute__((ext_vector_type(4)));
typedef float f32x4  __attribute__((ext_vector_type(4)));

// ---------- problem constants ----------
static constexpr float SCALE = 0.17677669529663687f; // 32^-0.5

__device__ __forceinline__ void gload_lds16(const void* g, void* l) {
  __builtin_amdgcn_global_load_lds(
      (const __attribute__((address_space(1))) unsigned int*)g,
      (__attribute__((address_space(3))) unsigned int*)l, 16, 0, 0);
}

__device__ __forceinline__ size_t win_to_nat(int t) {
  int win = t / 49; int n = t - win * 49;
  int bb = win >> 6; int wimg = win & 63;
  int hb = wimg >> 3, wb = wimg & 7;
  int nr = n / 7, nc = n - nr * 7;
  int hh = hb * 7 + nr + 3; if (hh >= 56) hh -= 56;
  int ww = wb * 7 + nc + 3; if (ww >= 56) ww -= 56;
  return (size_t)bb * 3136 + (size_t)hh * 56 + ww;
}

__device__ __forceinline__ float gelu_fast(float x) {
  float t = __expf(-1.702f * x);
  return x / (1.f + t);
}

__device__ __forceinline__ float b2f(short s) {
  unsigned int u = ((unsigned int)(unsigned short)s) << 16;
  return __uint_as_float(u);
}
__device__ __forceinline__ short f2b(float f) {
  return (short)__bfloat16_as_ushort(__float2bfloat16(f));
}

// ---------- LDS-tiled weight transpose+cast ----------
__global__ __launch_bounds__(256)
void k_transpose(const float* __restrict__ W, __hip_bfloat16* __restrict__ Wt,
                 int K, int N) {
  __shared__ float tile[32][33];
  int tx = threadIdx.x & 31, ty = threadIdx.x >> 5;
  int tc = blockIdx.x, tr = blockIdx.y;
#pragma unroll
  for (int r = 0; r < 32; r += 8)
    tile[r + ty][tx] = W[(size_t)(tr * 32 + r + ty) * N + tc * 32 + tx];
  __syncthreads();
#pragma unroll
  for (int r = 0; r < 32; r += 8)
    Wt[(size_t)(tc * 32 + r + ty) * K + tr * 32 + tx] =
        __float2bfloat16(tile[tx][r + ty]);
}

// ---------- LN1 + roll + window partition ----------
__global__ __launch_bounds__(256)
void k_ln1(const float* __restrict__ x, const float* __restrict__ gw,
           const float* __restrict__ bw, __hip_bfloat16* __restrict__ xw) {
  int lane = threadIdx.x & 63;
  int t = blockIdx.x * 4 + (threadIdx.x >> 6);
  size_t nt = win_to_nat(t);
  const float* xr = x + nt * 384;
  float4 a  = *(const float4*)(xr + lane * 4);
  float2 c2 = *(const float2*)(xr + 256 + lane * 2);
  float v[6] = {a.x, a.y, a.z, a.w, c2.x, c2.y};
  int c0 = lane * 4, c1 = 256 + lane * 2;
  int ch[6] = {c0, c0 + 1, c0 + 2, c0 + 3, c1, c1 + 1};
  float s = 0.f, q = 0.f;
#pragma unroll
  for (int i = 0; i < 6; i++) { s += v[i]; q += v[i] * v[i]; }
#pragma unroll
  for (int m = 1; m < 64; m <<= 1) { s += __shfl_xor(s, m); q += __shfl_xor(q, m); }
  float mean = s * (1.f / 384.f);
  float rstd = rsqrtf(q * (1.f / 384.f) - mean * mean + 1e-5f);
  __hip_bfloat16* o = xw + (size_t)t * 384;
#pragma unroll
  for (int i = 0; i < 6; i++)
    o[ch[i]] = __float2bfloat16((v[i] - mean) * rstd * gw[ch[i]] + bw[ch[i]]);
}

// ---------- double LN (reads bf16 x_res) ----------
__global__ __launch_bounds__(256)
void k_ln2ff(const __hip_bfloat16* __restrict__ xres, const float* __restrict__ g2,
             const float* __restrict__ b2, const float* __restrict__ gf,
             const float* __restrict__ bf_, __hip_bfloat16* __restrict__ yln) {
  int lane = threadIdx.x & 63;
  int t = blockIdx.x * 4 + (threadIdx.x >> 6);
  const __hip_bfloat16* xr = xres + (size_t)t * 384;
  short4v a = *(const short4v*)(xr + lane * 4);
  int c2 = *(const int*)(xr + 256 + lane * 2);
  float v[6] = {b2f(a[0]), b2f(a[1]), b2f(a[2]), b2f(a[3]),
                b2f((short)(c2 & 0xffff)), b2f((short)((unsigned)c2 >> 16))};
  int c0 = lane * 4, c1 = 256 + lane * 2;
  int ch[6] = {c0, c0 + 1, c0 + 2, c0 + 3, c1, c1 + 1};
  float s = 0.f, q = 0.f;
#pragma unroll
  for (int i = 0; i < 6; i++) { s += v[i]; q += v[i] * v[i]; }
#pragma unroll
  for (int m = 1; m < 64; m <<= 1) { s += __shfl_xor(s, m); q += __shfl_xor(q, m); }
  float mean = s * (1.f / 384.f);
  float rstd = rsqrtf(q * (1.f / 384.f) - mean * mean + 1e-5f);
  float y1[6];
  s = 0.f; q = 0.f;
#pragma unroll
  for (int i = 0; i < 6; i++) {
    y1[i] = (v[i] - mean) * rstd * g2[ch[i]] + b2[ch[i]];
    s += y1[i]; q += y1[i] * y1[i];
  }
#pragma unroll
  for (int m = 1; m < 64; m <<= 1) { s += __shfl_xor(s, m); q += __shfl_xor(q, m); }
  float m2 = s * (1.f / 384.f);
  float r2 = rsqrtf(q * (1.f / 384.f) - m2 * m2 + 1e-6f);
  __hip_bfloat16* o = yln + (size_t)t * 384;
#pragma unroll
  for (int i = 0; i < 6; i++)
    o[ch[i]] = __float2bfloat16((y1[i] - m2) * r2 * gf[ch[i]] + bf_[ch[i]]);
}

// ---------- R11 GEMM (best measured) + rowOff for M-chunked launches ----------
enum { EPI_QKV = 0, EPI_PROJ = 1, EPI_FF1 = 2, EPI_FF2 = 3 };

template <int EPI>
__global__ __launch_bounds__(256)
void k_gemm(const __hip_bfloat16* __restrict__ A, const __hip_bfloat16* __restrict__ Wt,
            const float* __restrict__ bias, int K, int nCol, int cpx, int rowOff,
            const float* __restrict__ aux,        // PROJ: x (f32, global)
            const __hip_bfloat16* __restrict__ auxb, // FF2: x_res (bf16)
            float* __restrict__ out_f,            // FF2: final out
            __hip_bfloat16* __restrict__ out_b) { // QKV: q; FF1: hbuf; PROJ: x_res
  __shared__ __hip_bfloat16 LB[24576];
  int tid = threadIdx.x;
  int lane = tid & 63, w = tid >> 6;
  int g = lane >> 4, r16 = lane & 15;
  int wr = w >> 1, wc = w & 1;

  int bid = blockIdx.x;
  int wg = (bid & 7) * cpx + (bid >> 3);   // XCD swizzle (nwg % 8 == 0)
  int rB = wg / nCol;
  int rowBlk = rB * 128;
  int colBlk = (wg - rB * nCol) * 128;

  int s2 = (tid & 7) ^ ((tid >> 3) & 7);
  int srow = 2 * (tid >> 3) + (s2 >> 2);
  int cch = s2 & 3;
  const __hip_bfloat16* PA = A + (size_t)(rowBlk + srow) * K + cch * 8;
  const __hip_bfloat16* PB = Wt + (size_t)(colBlk + srow) * K + cch * 8;

#define STG(NB, T)                                                            \
  {                                                                           \
    int k0s = (T) << 5;                                                       \
    _Pragma("unroll") for (int j = 0; j < 2; j++) {                           \
      gload_lds16(PA + (size_t)j * 64 * K + k0s, &LB[(NB) * 4096 + j * 2048 + w * 512]); \
      gload_lds16(PB + (size_t)j * 64 * K + k0s, &LB[12288 + (NB) * 4096 + j * 2048 + w * 512]); \
    }                                                                         \
  }

  int rslot = (g + ((r16 & 1) << 2)) ^ (r16 >> 1);
  int aBase = (wr * 32 + (r16 >> 1)) * 64 + rslot * 8;
  int bBase = 12288 + (wc * 32 + (r16 >> 1)) * 64 + rslot * 8;

  f32x4 acc[4][4] = {};
  const int nt = K >> 5;   // 12 or 48

  STG(0, 0)
  STG(1, 1)

#define STEP(CB, SB, T)                                                       \
  {                                                                           \
    if ((T) + 2 < nt) {                                                       \
      STG(SB, (T) + 2)                                                        \
      asm volatile("s_waitcnt vmcnt(8)" ::: "memory");                        \
    } else if ((T) + 1 < nt) {                                                \
      asm volatile("s_waitcnt vmcnt(4)" ::: "memory");                        \
    } else {                                                                  \
      asm volatile("s_waitcnt vmcnt(0)" ::: "memory");                        \
    }                                                                         \
    __builtin_amdgcn_s_barrier();                                             \
    bf16x8 a[4], b[4];                                                        \
    _Pragma("unroll") for (int mi = 0; mi < 4; mi++)                          \
      a[mi] = *(const bf16x8*)(&LB[(CB) * 4096 + aBase + mi * 512]);          \
    _Pragma("unroll") for (int ni = 0; ni < 4; ni++)                          \
      b[ni] = *(const bf16x8*)(&LB[(CB) * 4096 + bBase + ni * 512]);          \
    __builtin_amdgcn_s_setprio(1);                                            \
    _Pragma("unroll") for (int mi = 0; mi < 4; mi++)                          \
      _Pragma("unroll") for (int ni = 0; ni < 4; ni++)                        \
        acc[mi][ni] = __builtin_amdgcn_mfma_f32_16x16x32_bf16(                \
            b[ni], a[mi], acc[mi][ni], 0, 0, 0);                              \
    __builtin_amdgcn_s_setprio(0);                                            \
    __builtin_amdgcn_s_barrier();                                             \
  }

  for (int t = 0; t < nt; t += 3) {
    STEP(0, 2, t)
    STEP(1, 0, t + 1)
    STEP(2, 1, t + 2)
  }
#undef STEP
#undef STG

  // ---- vectorized epilogue via per-wave LDS tiles ----
  if constexpr (EPI == EPI_QKV || EPI == EPI_FF1) {
    __hip_bfloat16* EP = &LB[w * 4096];
#pragma unroll
    for (int ni = 0; ni < 4; ni++) {
      float4 b4 = *(const float4*)(bias + colBlk + wc * 64 + ni * 16 + g * 4);
#pragma unroll
      for (int mi = 0; mi < 4; mi++) {
        float v0 = acc[mi][ni][0] + b4.x, v1 = acc[mi][ni][1] + b4.y,
              v2 = acc[mi][ni][2] + b4.z, v3 = acc[mi][ni][3] + b4.w;
        if constexpr (EPI == EPI_FF1) {
          v0 = gelu_fast(v0); v1 = gelu_fast(v1);
          v2 = gelu_fast(v2); v3 = gelu_fast(v3);
        }
        short4v s4 = {f2b(v0), f2b(v1), f2b(v2), f2b(v3)};
        int row = mi * 16 + r16;
        int ch8 = (ni * 2 + (g >> 1)) ^ (row & 7);
        *(short4v*)(&EP[row * 64 + ch8 * 8 + (g & 1) * 4]) = s4;
      }
    }
#pragma unroll
    for (int j = 0; j < 8; j++) {
      int r = j * 8 + (lane >> 3);
      bf16x8 vv = *(const bf16x8*)(&EP[r * 64 + ((lane & 7) ^ (r & 7)) * 8]);
      int grow = rowBlk + wr * 64 + r;
      int col0 = colBlk + wc * 64 + (lane & 7) * 8;
      if constexpr (EPI == EPI_QKV) {
        int winr = grow / 49, nn = grow - winr * 49;
        int which = col0 / 384; int rem = col0 - which * 384;
        int hh = rem >> 5, dd = rem & 31;
        size_t off = (((size_t)winr * 12 + hh) * 49 + nn) * 32 + dd;
        *(bf16x8*)(out_b + (size_t)which * 38535168u + off) = vv;
      } else {
        *(bf16x8*)(out_b + (size_t)grow * 1536 + col0) = vv;
      }
    }
  } else {
    float* EPF = (float*)LB + w * 2048;
#pragma unroll
    for (int half = 0; half < 2; half++) {
#pragma unroll
      for (int ni = 0; ni < 4; ni++) {
        float4 b4 = *(const float4*)(bias + colBlk + wc * 64 + ni * 16 + g * 4);
#pragma unroll
        for (int mi2 = 0; mi2 < 2; mi2++) {
          int mi = half * 2 + mi2;
          f32x4 v = acc[mi][ni];
          v[0] += b4.x; v[1] += b4.y; v[2] += b4.z; v[3] += b4.w;
          int row = mi2 * 16 + r16;
          int ch4 = (ni * 4 + g) ^ r16;
          *(f32x4*)(&EPF[row * 64 + ch4 * 4]) = v;
        }
      }
#pragma unroll
      for (int j = 0; j < 8; j++) {
        int r = j * 4 + g;
        f32x4 vv = *(const f32x4*)(&EPF[r * 64 + ((r16 ^ (r & 15)) * 4)]);
        int grow = rowBlk + wr * 64 + half * 32 + r;
        int col0 = colBlk + wc * 64 + r16 * 4;
        if constexpr (EPI == EPI_PROJ) {
          size_t nt2 = win_to_nat(grow + rowOff);   // global token
          const float4 a4 = *(const float4*)(aux + nt2 * 384 + col0);
          short4v s4 = {f2b(vv[0] + a4.x), f2b(vv[1] + a4.y),
                        f2b(vv[2] + a4.z), f2b(vv[3] + a4.w)};
          *(short4v*)(out_b + nt2 * 384 + col0) = s4;
        } else {
          short4v a4 = *(const short4v*)(auxb + (size_t)grow * 384 + col0);
          float4 o4 = {vv[0] + b2f(a4[0]), vv[1] + b2f(a4[1]),
                       vv[2] + b2f(a4[2]), vv[3] + b2f(a4[3])};
          *(float4*)(out_f + (size_t)grow * 384 + col0) = o4;
        }
      }
    }
  }
}

// ---------- windowed attention: 1 wave per (window, head) ----------
// chunk-safe: all pointers pre-offset; wimg = wi & 63 valid when the chunk
// start window is a multiple of 64 (1024 is).
__global__ __launch_bounds__(256)
void k_attn(const __hip_bfloat16* __restrict__ q, const __hip_bfloat16* __restrict__ k,
            const __hip_bfloat16* __restrict__ v, const float* __restrict__ rpb,
            __hip_bfloat16* __restrict__ o) {
  __shared__ __hip_bfloat16 P[4][64][72];
  int tid = threadIdx.x;
  int lane = tid & 63, wave = tid >> 6;
  int g = lane >> 4, r16 = lane & 15;
  int gid = blockIdx.x * 4 + wave;
  int wi = gid / 12, h = gid - (gid / 12) * 12;
  int wimg = wi & 63;
  int hb = wimg >> 3, wb = wimg & 7;
  size_t base = ((size_t)wi * 12 + h) * (49 * 32);
  const __hip_bfloat16* qb = q + base;
  const __hip_bfloat16* kb = k + base;
  const __hip_bfloat16* vb = v + base;

  bf16x8 zf = {0, 0, 0, 0, 0, 0, 0, 0};
  bf16x8 qf[4], kf[4];
#pragma unroll
  for (int mi = 0; mi < 4; mi++) {
    int row = mi * 16 + r16;
    qf[mi] = (row < 49) ? *(const bf16x8*)(qb + row * 32 + g * 8) : zf;
    kf[mi] = (row < 49) ? *(const bf16x8*)(kb + row * 32 + g * 8) : zf;
  }
  f32x4 fz = {0.f, 0.f, 0.f, 0.f};
  f32x4 S[4][4];
#pragma unroll
  for (int mi = 0; mi < 4; mi++)
#pragma unroll
    for (int ni = 0; ni < 4; ni++)
      S[mi][ni] = __builtin_amdgcn_mfma_f32_16x16x32_bf16(qf[mi], kf[ni], fz, 0, 0, 0);

  int kiA[4], kjA[4], rkA[4], cvA[4];
#pragma unroll
  for (int ni = 0; ni < 4; ni++) {
    int col = ni * 16 + r16;
    cvA[ni] = (col < 49);
    int ki = col / 7, kj = col - (col / 7) * 7;
    kiA[ni] = ki; kjA[ni] = kj;
    int hg = hb * 7 + ki, wg = wb * 7 + kj;
    int rh = (hg < 49) ? 0 : ((hg < 53) ? 1 : 2);
    int rw = (wg < 49) ? 0 : ((wg < 53) ? 1 : 2);
    rkA[ni] = rh * 3 + rw;
  }

#pragma unroll
  for (int mi = 0; mi < 4; mi++) {
#pragma unroll
    for (int rr = 0; rr < 4; rr++) {
      int row = mi * 16 + g * 4 + rr;
      float sv[4];
      float mx = -1e30f;
      int qi = row / 7, qj = row - (row / 7) * 7;
      int hgq = hb * 7 + qi, wgq = wb * 7 + qj;
      int rhq = (hgq < 49) ? 0 : ((hgq < 53) ? 1 : 2);
      int rwq = (wgq < 49) ? 0 : ((wgq < 53) ? 1 : 2);
      int rq = rhq * 3 + rwq;
#pragma unroll
      for (int ni = 0; ni < 4; ni++) {
        float s = -1e30f;
        if (row < 49 && cvA[ni]) {
          int idx = (qi - kiA[ni] + 6) * 13 + (qj - kjA[ni] + 6);
          float maskv = (rq != rkA[ni]) ? -100.f : 0.f;
          s = S[mi][ni][rr] * SCALE + rpb[idx * 12 + h] + maskv;
        }
        sv[ni] = s;
        mx = fmaxf(mx, s);
      }
#pragma unroll
      for (int m = 1; m <= 8; m <<= 1) mx = fmaxf(mx, __shfl_xor(mx, m));
      float sum = 0.f;
#pragma unroll
      for (int ni = 0; ni < 4; ni++) {
        float p = __expf(sv[ni] - mx);
        sv[ni] = p; sum += p;
      }
#pragma unroll
      for (int m = 1; m <= 8; m <<= 1) sum += __shfl_xor(sum, m);
      float inv = 1.f / sum;
#pragma unroll
      for (int ni = 0; ni < 4; ni++)
        P[wave][row][ni * 16 + r16] = __float2bfloat16(sv[ni] * inv);
    }
  }

  f32x4 O[4][2] = {};
#pragma unroll
  for (int ks = 0; ks < 2; ks++) {
    bf16x8 pf[4];
#pragma unroll
    for (int mi = 0; mi < 4; mi++)
      pf[mi] = *(const bf16x8*)(&P[wave][mi * 16 + r16][ks * 32 + g * 8]);
#pragma unroll
    for (int ni = 0; ni < 2; ni++) {
      bf16x8 vf = zf;
#pragma unroll
      for (int j = 0; j < 8; j++) {
        int m = ks * 32 + g * 8 + j;
        if (m < 49) vf[j] = ((const short*)vb)[m * 32 + ni * 16 + r16];
      }
#pragma unroll
      for (int mi = 0; mi < 4; mi++)
        O[mi][ni] = __builtin_amdgcn_mfma_f32_16x16x32_bf16(pf[mi], vf, O[mi][ni], 0, 0, 0);
    }
  }

#pragma unroll
  for (int mi = 0; mi < 4; mi++)
#pragma unroll
    for (int rr = 0; rr < 4; rr++) {
      int row = mi * 16 + g * 4 + rr;
      if (row < 49) {
#pragma unroll
        for (int ni = 0; ni < 2; ni++) {
          int col = ni * 16 + r16;
          o[(((size_t)wi * 49 + row) * 12 + h) * 32 + col] = __float2bfloat16(O[mi][ni][rr]);
        }
      }
    }
}

// ---------- host launch ----------
extern "C" void kernel_launch(void* const* d_in, const int* in_sizes, int n_in,
                              void* d_out, int out_size, void* d_ws, size_t ws_size,
                              hipStream_t stream) {
  const float* x      = (const float*)d_in[0];
  const float* ln1_g  = (const float*)d_in[1];
  const float* ln1_b  = (const float*)d_in[2];
  const float* qkv_w  = (const float*)d_in[3];
  const float* qkv_b  = (const float*)d_in[4];
  const float* proj_w = (const float*)d_in[5];
  const float* proj_b = (const float*)d_in[6];
  const float* rpb    = (const float*)d_in[7];
  const float* ln2_g  = (const float*)d_in[8];
  const float* ln2_b  = (const float*)d_in[9];
  const float* ffg    = (const float*)d_in[10];
  const float* ffb    = (const float*)d_in[11];
  const float* ff1_w  = (const float*)d_in[12];
  const float* ff1_b  = (const float*)d_in[13];
  const float* ff2_w  = (const float*)d_in[14];
  const float* ff2_b  = (const float*)d_in[15];
  float* out = (float*)d_out;

  char* ws = (char*)d_ws;
  __hip_bfloat16* xw     = (__hip_bfloat16*)ws;
  __hip_bfloat16* qbuf   = (__hip_bfloat16*)(ws + 77070336u);
  __hip_bfloat16* kbuf   = qbuf + 38535168u;
  __hip_bfloat16* vbuf   = kbuf + 38535168u;
  __hip_bfloat16* attn_o = xw;
  __hip_bfloat16* hbuf   = (__hip_bfloat16*)ws;
  __hip_bfloat16* x_res  = (__hip_bfloat16*)(ws + 308281344u);
  __hip_bfloat16* yln    = (__hip_bfloat16*)(ws + 462422016u);
  __hip_bfloat16* qkv_wt = (__hip_bfloat16*)(ws + 539492352u);
  __hip_bfloat16* proj_wt = qkv_wt + 442368u;
  __hip_bfloat16* ff1_wt  = proj_wt + 147456u;
  __hip_bfloat16* ff2_wt  = ff1_wt + 589824u;

  // weight prep
  k_transpose<<<dim3(1152 / 32, 384 / 32), dim3(256), 0, stream>>>(qkv_w, qkv_wt, 384, 1152);
  k_transpose<<<dim3(384 / 32, 384 / 32), dim3(256), 0, stream>>>(proj_w, proj_wt, 384, 384);
  k_transpose<<<dim3(1536 / 32, 384 / 32), dim3(256), 0, stream>>>(ff1_w, ff1_wt, 384, 1536);
  k_transpose<<<dim3(384 / 32, 1536 / 32), dim3(256), 0, stream>>>(ff2_w, ff2_wt, 1536, 384);

  // LN1 + shift + window partition (full)
  k_ln1<<<dim3(25088), dim3(256), 0, stream>>>(x, ln1_g, ln1_b, xw);

  // ---- M-chunked attention pipeline: halves keep q/k/v (116MB) + attn_o
  // (38MB) L3-resident between producer and consumer. ----
  // Chunk boundaries: tokens 50176 = windows 1024 (multiple of 64 -> wimg ok).
  const size_t TOK = 50176, QOFF = 1024u * 18816u;  // window-chunk elem offset
  for (int c = 0; c < 2; c++) {
    size_t to = c * TOK;
    const __hip_bfloat16* xwA = xw + to * 384;
    __hip_bfloat16* qb_ = qbuf + c * QOFF;
    // QKV: M=50176 -> 392 row-blocks x 9 -> nwg 3528
    k_gemm<EPI_QKV><<<dim3(3528), dim3(256), 0, stream>>>(
        xwA, qkv_wt, qkv_b, 384, 9, 3528 / 8, 0, nullptr, nullptr, nullptr, qb_);
    // attention: 1024 windows x 12 heads / 4 per block = 3072
    k_attn<<<dim3(3072), dim3(256), 0, stream>>>(
        qbuf + c * QOFF, kbuf + c * QOFF, vbuf + c * QOFF, rpb, attn_o + to * 384);
    // proj: nwg = 392*3 = 1176; rowOff for win_to_nat
    k_gemm<EPI_PROJ><<<dim3(1176), dim3(256), 0, stream>>>(
        attn_o + to * 384, proj_wt, proj_b, 384, 3, 1176 / 8, (int)to,
        x, nullptr, nullptr, x_res);
  }

  // LN2 + ffLN (full)
  k_ln2ff<<<dim3(25088), dim3(256), 0, stream>>>(x_res, ln2_g, ln2_b, ffg, ffb, yln);

  // ---- M-chunked FFN: hbuf half (154MB) stays L3-resident for FF2 ----
  for (int c = 0; c < 2; c++) {
    size_t to = c * TOK;
    k_gemm<EPI_FF1><<<dim3(4704), dim3(256), 0, stream>>>(
        yln + to * 384, ff1_wt, ff1_b, 384, 12, 4704 / 8, 0,
        nullptr, nullptr, nullptr, hbuf + to * 1536);
    k_gemm<EPI_FF2><<<dim3(1176), dim3(256), 0, stream>>>(
        hbuf + to * 1536, ff2_wt, ff2_b, 1536, 3, 1176 / 8, 0,
        nullptr, x_res + to * 384, out + to * 384, nullptr);
  }
}

// Round 18
// 836.425 us; speedup vs baseline: 1.4562x; 1.0330x over previous
//
#include <hip/hip_runtime.h>
#include <hip/hip_bf16.h>

typedef short bf16x8 __attribute__((ext_vector_type(8)));
typedef short short4v __attribute__((ext_vector_type(4)));
typedef float f32x4  __attribute__((ext_vector_type(4)));

// ---------- problem constants ----------
static constexpr float SCALE = 0.17677669529663687f; // 32^-0.5

__device__ __forceinline__ void gload_lds16(const void* g, void* l) {
  __builtin_amdgcn_global_load_lds(
      (const __attribute__((address_space(1))) unsigned int*)g,
      (__attribute__((address_space(3))) unsigned int*)l, 16, 0, 0);
}

__device__ __forceinline__ size_t win_to_nat(int t) {
  int win = t / 49; int n = t - win * 49;
  int bb = win >> 6; int wimg = win & 63;
  int hb = wimg >> 3, wb = wimg & 7;
  int nr = n / 7, nc = n - nr * 7;
  int hh = hb * 7 + nr + 3; if (hh >= 56) hh -= 56;
  int ww = wb * 7 + nc + 3; if (ww >= 56) ww -= 56;
  return (size_t)bb * 3136 + (size_t)hh * 56 + ww;
}

__device__ __forceinline__ float gelu_fast(float x) {
  float t = __expf(-1.702f * x);
  return x / (1.f + t);
}

__device__ __forceinline__ float b2f(short s) {
  unsigned int u = ((unsigned int)(unsigned short)s) << 16;
  return __uint_as_float(u);
}
__device__ __forceinline__ short f2b(float f) {
  return (short)__bfloat16_as_ushort(__float2bfloat16(f));
}

// ---------- fused weight transpose+cast: all 4 matrices, one launch ----------
// flat tile ranges: [0,432) qkv(K384,N1152) | [432,576) proj(384,384) |
// [576,1152) ff1(384,1536) | [1152,1728) ff2(1536,384)
__global__ __launch_bounds__(256)
void k_transpose_all(const float* __restrict__ qkv_w, const float* __restrict__ proj_w,
                     const float* __restrict__ ff1_w, const float* __restrict__ ff2_w,
                     __hip_bfloat16* __restrict__ qkv_t, __hip_bfloat16* __restrict__ proj_t,
                     __hip_bfloat16* __restrict__ ff1_t, __hip_bfloat16* __restrict__ ff2_t) {
  __shared__ float tile[32][33];
  int b = blockIdx.x;
  const float* W; __hip_bfloat16* Wt; int K, N, local;
  if (b < 432)       { W = qkv_w;  Wt = qkv_t;  K = 384;  N = 1152; local = b; }
  else if (b < 576)  { W = proj_w; Wt = proj_t; K = 384;  N = 384;  local = b - 432; }
  else if (b < 1152) { W = ff1_w;  Wt = ff1_t;  K = 384;  N = 1536; local = b - 576; }
  else               { W = ff2_w;  Wt = ff2_t;  K = 1536; N = 384;  local = b - 1152; }
  int nc = N >> 5;
  int tc = local % nc, tr = local / nc;
  int tx = threadIdx.x & 31, ty = threadIdx.x >> 5;
#pragma unroll
  for (int r = 0; r < 32; r += 8)
    tile[r + ty][tx] = W[(size_t)(tr * 32 + r + ty) * N + tc * 32 + tx];
  __syncthreads();
#pragma unroll
  for (int r = 0; r < 32; r += 8)
    Wt[(size_t)(tc * 32 + r + ty) * K + tr * 32 + tx] =
        __float2bfloat16(tile[tx][r + ty]);
}

// ---------- LN1 + roll + window partition (chunked via tOff) ----------
__global__ __launch_bounds__(256)
void k_ln1(const float* __restrict__ x, const float* __restrict__ gw,
           const float* __restrict__ bw, __hip_bfloat16* __restrict__ xw, int tOff) {
  int lane = threadIdx.x & 63;
  int t = tOff + blockIdx.x * 4 + (threadIdx.x >> 6);
  size_t nt = win_to_nat(t);
  const float* xr = x + nt * 384;
  float4 a  = *(const float4*)(xr + lane * 4);
  float2 c2 = *(const float2*)(xr + 256 + lane * 2);
  float v[6] = {a.x, a.y, a.z, a.w, c2.x, c2.y};
  int c0 = lane * 4, c1 = 256 + lane * 2;
  int ch[6] = {c0, c0 + 1, c0 + 2, c0 + 3, c1, c1 + 1};
  float s = 0.f, q = 0.f;
#pragma unroll
  for (int i = 0; i < 6; i++) { s += v[i]; q += v[i] * v[i]; }
#pragma unroll
  for (int m = 1; m < 64; m <<= 1) { s += __shfl_xor(s, m); q += __shfl_xor(q, m); }
  float mean = s * (1.f / 384.f);
  float rstd = rsqrtf(q * (1.f / 384.f) - mean * mean + 1e-5f);
  __hip_bfloat16* o = xw + (size_t)t * 384;
#pragma unroll
  for (int i = 0; i < 6; i++)
    o[ch[i]] = __float2bfloat16((v[i] - mean) * rstd * gw[ch[i]] + bw[ch[i]]);
}

// ---------- double LN (bf16 x_res in, chunked via tOff) ----------
__global__ __launch_bounds__(256)
void k_ln2ff(const __hip_bfloat16* __restrict__ xres, const float* __restrict__ g2,
             const float* __restrict__ b2, const float* __restrict__ gf,
             const float* __restrict__ bf_, __hip_bfloat16* __restrict__ yln, int tOff) {
  int lane = threadIdx.x & 63;
  int t = tOff + blockIdx.x * 4 + (threadIdx.x >> 6);
  const __hip_bfloat16* xr = xres + (size_t)t * 384;
  short4v a = *(const short4v*)(xr + lane * 4);
  int c2 = *(const int*)(xr + 256 + lane * 2);
  float v[6] = {b2f(a[0]), b2f(a[1]), b2f(a[2]), b2f(a[3]),
                b2f((short)(c2 & 0xffff)), b2f((short)((unsigned)c2 >> 16))};
  int c0 = lane * 4, c1 = 256 + lane * 2;
  int ch[6] = {c0, c0 + 1, c0 + 2, c0 + 3, c1, c1 + 1};
  float s = 0.f, q = 0.f;
#pragma unroll
  for (int i = 0; i < 6; i++) { s += v[i]; q += v[i] * v[i]; }
#pragma unroll
  for (int m = 1; m < 64; m <<= 1) { s += __shfl_xor(s, m); q += __shfl_xor(q, m); }
  float mean = s * (1.f / 384.f);
  float rstd = rsqrtf(q * (1.f / 384.f) - mean * mean + 1e-5f);
  float y1[6];
  s = 0.f; q = 0.f;
#pragma unroll
  for (int i = 0; i < 6; i++) {
    y1[i] = (v[i] - mean) * rstd * g2[ch[i]] + b2[ch[i]];
    s += y1[i]; q += y1[i] * y1[i];
  }
#pragma unroll
  for (int m = 1; m < 64; m <<= 1) { s += __shfl_xor(s, m); q += __shfl_xor(q, m); }
  float m2 = s * (1.f / 384.f);
  float r2 = rsqrtf(q * (1.f / 384.f) - m2 * m2 + 1e-6f);
  __hip_bfloat16* o = yln + (size_t)t * 384;
#pragma unroll
  for (int i = 0; i < 6; i++)
    o[ch[i]] = __float2bfloat16((y1[i] - m2) * r2 * gf[ch[i]] + bf_[ch[i]]);
}

// ---------- R11 GEMM (best measured); setprio removed (m190: null/neg here) ----
enum { EPI_QKV = 0, EPI_PROJ = 1, EPI_FF1 = 2, EPI_FF2 = 3 };

template <int EPI>
__global__ __launch_bounds__(256)
void k_gemm(const __hip_bfloat16* __restrict__ A, const __hip_bfloat16* __restrict__ Wt,
            const float* __restrict__ bias, int K, int nCol, int cpx, int rowOff,
            const float* __restrict__ aux,        // PROJ: x (f32, global)
            const __hip_bfloat16* __restrict__ auxb, // FF2: x_res (bf16)
            float* __restrict__ out_f,            // FF2: final out
            __hip_bfloat16* __restrict__ out_b) { // QKV: q; FF1: hbuf; PROJ: x_res
  __shared__ __hip_bfloat16 LB[24576];
  int tid = threadIdx.x;
  int lane = tid & 63, w = tid >> 6;
  int g = lane >> 4, r16 = lane & 15;
  int wr = w >> 1, wc = w & 1;

  int bid = blockIdx.x;
  int wg = (bid & 7) * cpx + (bid >> 3);   // XCD swizzle (nwg % 8 == 0)
  int rB = wg / nCol;
  int rowBlk = rB * 128;
  int colBlk = (wg - rB * nCol) * 128;

  int s2 = (tid & 7) ^ ((tid >> 3) & 7);
  int srow = 2 * (tid >> 3) + (s2 >> 2);
  int cch = s2 & 3;
  const __hip_bfloat16* PA = A + (size_t)(rowBlk + srow) * K + cch * 8;
  const __hip_bfloat16* PB = Wt + (size_t)(colBlk + srow) * K + cch * 8;

#define STG(NB, T)                                                            \
  {                                                                           \
    int k0s = (T) << 5;                                                       \
    _Pragma("unroll") for (int j = 0; j < 2; j++) {                           \
      gload_lds16(PA + (size_t)j * 64 * K + k0s, &LB[(NB) * 4096 + j * 2048 + w * 512]); \
      gload_lds16(PB + (size_t)j * 64 * K + k0s, &LB[12288 + (NB) * 4096 + j * 2048 + w * 512]); \
    }                                                                         \
  }

  int rslot = (g + ((r16 & 1) << 2)) ^ (r16 >> 1);
  int aBase = (wr * 32 + (r16 >> 1)) * 64 + rslot * 8;
  int bBase = 12288 + (wc * 32 + (r16 >> 1)) * 64 + rslot * 8;

  f32x4 acc[4][4] = {};
  const int nt = K >> 5;   // 12 or 48

  STG(0, 0)
  STG(1, 1)

#define STEP(CB, SB, T)                                                       \
  {                                                                           \
    if ((T) + 2 < nt) {                                                       \
      STG(SB, (T) + 2)                                                        \
      asm volatile("s_waitcnt vmcnt(8)" ::: "memory");                        \
    } else if ((T) + 1 < nt) {                                                \
      asm volatile("s_waitcnt vmcnt(4)" ::: "memory");                        \
    } else {                                                                  \
      asm volatile("s_waitcnt vmcnt(0)" ::: "memory");                        \
    }                                                                         \
    __builtin_amdgcn_s_barrier();                                             \
    bf16x8 a[4], b[4];                                                        \
    _Pragma("unroll") for (int mi = 0; mi < 4; mi++)                          \
      a[mi] = *(const bf16x8*)(&LB[(CB) * 4096 + aBase + mi * 512]);          \
    _Pragma("unroll") for (int ni = 0; ni < 4; ni++)                          \
      b[ni] = *(const bf16x8*)(&LB[(CB) * 4096 + bBase + ni * 512]);          \
    _Pragma("unroll") for (int mi = 0; mi < 4; mi++)                          \
      _Pragma("unroll") for (int ni = 0; ni < 4; ni++)                        \
        acc[mi][ni] = __builtin_amdgcn_mfma_f32_16x16x32_bf16(                \
            b[ni], a[mi], acc[mi][ni], 0, 0, 0);                              \
    __builtin_amdgcn_s_barrier();                                             \
  }

  for (int t = 0; t < nt; t += 3) {
    STEP(0, 2, t)
    STEP(1, 0, t + 1)
    STEP(2, 1, t + 2)
  }
#undef STEP
#undef STG

  // ---- vectorized epilogue via per-wave LDS tiles ----
  if constexpr (EPI == EPI_QKV || EPI == EPI_FF1) {
    __hip_bfloat16* EP = &LB[w * 4096];
#pragma unroll
    for (int ni = 0; ni < 4; ni++) {
      float4 b4 = *(const float4*)(bias + colBlk + wc * 64 + ni * 16 + g * 4);
#pragma unroll
      for (int mi = 0; mi < 4; mi++) {
        float v0 = acc[mi][ni][0] + b4.x, v1 = acc[mi][ni][1] + b4.y,
              v2 = acc[mi][ni][2] + b4.z, v3 = acc[mi][ni][3] + b4.w;
        if constexpr (EPI == EPI_FF1) {
          v0 = gelu_fast(v0); v1 = gelu_fast(v1);
          v2 = gelu_fast(v2); v3 = gelu_fast(v3);
        }
        short4v s4 = {f2b(v0), f2b(v1), f2b(v2), f2b(v3)};
        int row = mi * 16 + r16;
        int ch8 = (ni * 2 + (g >> 1)) ^ (row & 7);
        *(short4v*)(&EP[row * 64 + ch8 * 8 + (g & 1) * 4]) = s4;
      }
    }
#pragma unroll
    for (int j = 0; j < 8; j++) {
      int r = j * 8 + (lane >> 3);
      bf16x8 vv = *(const bf16x8*)(&EP[r * 64 + ((lane & 7) ^ (r & 7)) * 8]);
      int grow = rowBlk + wr * 64 + r;
      int col0 = colBlk + wc * 64 + (lane & 7) * 8;
      if constexpr (EPI == EPI_QKV) {
        int winr = grow / 49, nn = grow - winr * 49;
        int which = col0 / 384; int rem = col0 - which * 384;
        int hh = rem >> 5, dd = rem & 31;
        size_t off = (((size_t)winr * 12 + hh) * 49 + nn) * 32 + dd;
        *(bf16x8*)(out_b + (size_t)which * 38535168u + off) = vv;
      } else {
        *(bf16x8*)(out_b + (size_t)grow * 1536 + col0) = vv;
      }
    }
  } else {
    float* EPF = (float*)LB + w * 2048;
#pragma unroll
    for (int half = 0; half < 2; half++) {
#pragma unroll
      for (int ni = 0; ni < 4; ni++) {
        float4 b4 = *(const float4*)(bias + colBlk + wc * 64 + ni * 16 + g * 4);
#pragma unroll
        for (int mi2 = 0; mi2 < 2; mi2++) {
          int mi = half * 2 + mi2;
          f32x4 v = acc[mi][ni];
          v[0] += b4.x; v[1] += b4.y; v[2] += b4.z; v[3] += b4.w;
          int row = mi2 * 16 + r16;
          int ch4 = (ni * 4 + g) ^ r16;
          *(f32x4*)(&EPF[row * 64 + ch4 * 4]) = v;
        }
      }
#pragma unroll
      for (int j = 0; j < 8; j++) {
        int r = j * 4 + g;
        f32x4 vv = *(const f32x4*)(&EPF[r * 64 + ((r16 ^ (r & 15)) * 4)]);
        int grow = rowBlk + wr * 64 + half * 32 + r;
        int col0 = colBlk + wc * 64 + r16 * 4;
        if constexpr (EPI == EPI_PROJ) {
          size_t nt2 = win_to_nat(grow + rowOff);
          const float4 a4 = *(const float4*)(aux + nt2 * 384 + col0);
          short4v s4 = {f2b(vv[0] + a4.x), f2b(vv[1] + a4.y),
                        f2b(vv[2] + a4.z), f2b(vv[3] + a4.w)};
          *(short4v*)(out_b + nt2 * 384 + col0) = s4;
        } else {
          short4v a4 = *(const short4v*)(auxb + (size_t)grow * 384 + col0);
          float4 o4 = {vv[0] + b2f(a4[0]), vv[1] + b2f(a4[1]),
                       vv[2] + b2f(a4[2]), vv[3] + b2f(a4[3])};
          *(float4*)(out_f + (size_t)grow * 384 + col0) = o4;
        }
      }
    }
  }
}

// ---------- windowed attention: 1 wave per (window, head) ----------
__global__ __launch_bounds__(256)
void k_attn(const __hip_bfloat16* __restrict__ q, const __hip_bfloat16* __restrict__ k,
            const __hip_bfloat16* __restrict__ v, const float* __restrict__ rpb,
            __hip_bfloat16* __restrict__ o) {
  __shared__ __hip_bfloat16 P[4][64][72];
  int tid = threadIdx.x;
  int lane = tid & 63, wave = tid >> 6;
  int g = lane >> 4, r16 = lane & 15;
  int gid = blockIdx.x * 4 + wave;
  int wi = gid / 12, h = gid - (gid / 12) * 12;
  int wimg = wi & 63;
  int hb = wimg >> 3, wb = wimg & 7;
  size_t base = ((size_t)wi * 12 + h) * (49 * 32);
  const __hip_bfloat16* qb = q + base;
  const __hip_bfloat16* kb = k + base;
  const __hip_bfloat16* vb = v + base;

  bf16x8 zf = {0, 0, 0, 0, 0, 0, 0, 0};
  bf16x8 qf[4], kf[4];
#pragma unroll
  for (int mi = 0; mi < 4; mi++) {
    int row = mi * 16 + r16;
    qf[mi] = (row < 49) ? *(const bf16x8*)(qb + row * 32 + g * 8) : zf;
    kf[mi] = (row < 49) ? *(const bf16x8*)(kb + row * 32 + g * 8) : zf;
  }
  f32x4 fz = {0.f, 0.f, 0.f, 0.f};
  f32x4 S[4][4];
#pragma unroll
  for (int mi = 0; mi < 4; mi++)
#pragma unroll
    for (int ni = 0; ni < 4; ni++)
      S[mi][ni] = __builtin_amdgcn_mfma_f32_16x16x32_bf16(qf[mi], kf[ni], fz, 0, 0, 0);

  int kiA[4], kjA[4], rkA[4], cvA[4];
#pragma unroll
  for (int ni = 0; ni < 4; ni++) {
    int col = ni * 16 + r16;
    cvA[ni] = (col < 49);
    int ki = col / 7, kj = col - (col / 7) * 7;
    kiA[ni] = ki; kjA[ni] = kj;
    int hg = hb * 7 + ki, wg = wb * 7 + kj;
    int rh = (hg < 49) ? 0 : ((hg < 53) ? 1 : 2);
    int rw = (wg < 49) ? 0 : ((wg < 53) ? 1 : 2);
    rkA[ni] = rh * 3 + rw;
  }

#pragma unroll
  for (int mi = 0; mi < 4; mi++) {
#pragma unroll
    for (int rr = 0; rr < 4; rr++) {
      int row = mi * 16 + g * 4 + rr;
      float sv[4];
      float mx = -1e30f;
      int qi = row / 7, qj = row - (row / 7) * 7;
      int hgq = hb * 7 + qi, wgq = wb * 7 + qj;
      int rhq = (hgq < 49) ? 0 : ((hgq < 53) ? 1 : 2);
      int rwq = (wgq < 49) ? 0 : ((wgq < 53) ? 1 : 2);
      int rq = rhq * 3 + rwq;
#pragma unroll
      for (int ni = 0; ni < 4; ni++) {
        float s = -1e30f;
        if (row < 49 && cvA[ni]) {
          int idx = (qi - kiA[ni] + 6) * 13 + (qj - kjA[ni] + 6);
          float maskv = (rq != rkA[ni]) ? -100.f : 0.f;
          s = S[mi][ni][rr] * SCALE + rpb[idx * 12 + h] + maskv;
        }
        sv[ni] = s;
        mx = fmaxf(mx, s);
      }
#pragma unroll
      for (int m = 1; m <= 8; m <<= 1) mx = fmaxf(mx, __shfl_xor(mx, m));
      float sum = 0.f;
#pragma unroll
      for (int ni = 0; ni < 4; ni++) {
        float p = __expf(sv[ni] - mx);
        sv[ni] = p; sum += p;
      }
#pragma unroll
      for (int m = 1; m <= 8; m <<= 1) sum += __shfl_xor(sum, m);
      float inv = 1.f / sum;
#pragma unroll
      for (int ni = 0; ni < 4; ni++)
        P[wave][row][ni * 16 + r16] = __float2bfloat16(sv[ni] * inv);
    }
  }

  f32x4 O[4][2] = {};
#pragma unroll
  for (int ks = 0; ks < 2; ks++) {
    bf16x8 pf[4];
#pragma unroll
    for (int mi = 0; mi < 4; mi++)
      pf[mi] = *(const bf16x8*)(&P[wave][mi * 16 + r16][ks * 32 + g * 8]);
#pragma unroll
    for (int ni = 0; ni < 2; ni++) {
      bf16x8 vf = zf;
#pragma unroll
      for (int j = 0; j < 8; j++) {
        int m = ks * 32 + g * 8 + j;
        if (m < 49) vf[j] = ((const short*)vb)[m * 32 + ni * 16 + r16];
      }
#pragma unroll
      for (int mi = 0; mi < 4; mi++)
        O[mi][ni] = __builtin_amdgcn_mfma_f32_16x16x32_bf16(pf[mi], vf, O[mi][ni], 0, 0, 0);
    }
  }

#pragma unroll
  for (int mi = 0; mi < 4; mi++)
#pragma unroll
    for (int rr = 0; rr < 4; rr++) {
      int row = mi * 16 + g * 4 + rr;
      if (row < 49) {
#pragma unroll
        for (int ni = 0; ni < 2; ni++) {
          int col = ni * 16 + r16;
          o[(((size_t)wi * 49 + row) * 12 + h) * 32 + col] = __float2bfloat16(O[mi][ni][rr]);
        }
      }
    }
}

// ---------- host launch ----------
extern "C" void kernel_launch(void* const* d_in, const int* in_sizes, int n_in,
                              void* d_out, int out_size, void* d_ws, size_t ws_size,
                              hipStream_t stream) {
  const float* x      = (const float*)d_in[0];
  const float* ln1_g  = (const float*)d_in[1];
  const float* ln1_b  = (const float*)d_in[2];
  const float* qkv_w  = (const float*)d_in[3];
  const float* qkv_b  = (const float*)d_in[4];
  const float* proj_w = (const float*)d_in[5];
  const float* proj_b = (const float*)d_in[6];
  const float* rpb    = (const float*)d_in[7];
  const float* ln2_g  = (const float*)d_in[8];
  const float* ln2_b  = (const float*)d_in[9];
  const float* ffg    = (const float*)d_in[10];
  const float* ffb    = (const float*)d_in[11];
  const float* ff1_w  = (const float*)d_in[12];
  const float* ff1_b  = (const float*)d_in[13];
  const float* ff2_w  = (const float*)d_in[14];
  const float* ff2_b  = (const float*)d_in[15];
  float* out = (float*)d_out;

  char* ws = (char*)d_ws;
  __hip_bfloat16* xw     = (__hip_bfloat16*)ws;
  __hip_bfloat16* qbuf   = (__hip_bfloat16*)(ws + 77070336u);
  __hip_bfloat16* kbuf   = qbuf + 38535168u;
  __hip_bfloat16* vbuf   = kbuf + 38535168u;
  __hip_bfloat16* attn_o = xw;
  __hip_bfloat16* hbuf   = (__hip_bfloat16*)ws;
  __hip_bfloat16* x_res  = (__hip_bfloat16*)(ws + 308281344u);
  __hip_bfloat16* yln    = (__hip_bfloat16*)(ws + 462422016u);
  __hip_bfloat16* qkv_wt = (__hip_bfloat16*)(ws + 539492352u);
  __hip_bfloat16* proj_wt = qkv_wt + 442368u;
  __hip_bfloat16* ff1_wt  = proj_wt + 147456u;
  __hip_bfloat16* ff2_wt  = ff1_wt + 589824u;

  // fused weight prep (one launch)
  k_transpose_all<<<dim3(1728), dim3(256), 0, stream>>>(
      qkv_w, proj_w, ff1_w, ff2_w, qkv_wt, proj_wt, ff1_wt, ff2_wt);

  // ---- fully chunked per-half pipeline (half = 1024 windows = batch half;
  // window-chunk == natural-token chunk since roll is intra-image). Keeps
  // x, qkv, attn_o, x_res, yln, hbuf halves L3-resident producer->consumer. ----
  const size_t TOK = 50176, QOFF = 1024u * 18816u;
  for (int c = 0; c < 2; c++) {
    size_t to = c * TOK;
    // LN1 half: 12544 blocks x 4 tokens
    k_ln1<<<dim3(12544), dim3(256), 0, stream>>>(x, ln1_g, ln1_b, xw, (int)to);
    // QKV half: nwg 3528
    k_gemm<EPI_QKV><<<dim3(3528), dim3(256), 0, stream>>>(
        xw + to * 384, qkv_wt, qkv_b, 384, 9, 3528 / 8, 0,
        nullptr, nullptr, nullptr, qbuf + c * QOFF);
    // attention half: 3072 blocks
    k_attn<<<dim3(3072), dim3(256), 0, stream>>>(
        qbuf + c * QOFF, kbuf + c * QOFF, vbuf + c * QOFF, rpb, attn_o + to * 384);
    // proj half: nwg 1176 (+ residual from x, writes bf16 x_res)
    k_gemm<EPI_PROJ><<<dim3(1176), dim3(256), 0, stream>>>(
        attn_o + to * 384, proj_wt, proj_b, 384, 3, 1176 / 8, (int)to,
        x, nullptr, nullptr, x_res);
    // LN2+ffLN half
    k_ln2ff<<<dim3(12544), dim3(256), 0, stream>>>(
        x_res, ln2_g, ln2_b, ffg, ffb, yln, (int)to);
    // FF1 half
    k_gemm<EPI_FF1><<<dim3(4704), dim3(256), 0, stream>>>(
        yln + to * 384, ff1_wt, ff1_b, 384, 12, 4704 / 8, 0,
        nullptr, nullptr, nullptr, hbuf + to * 1536);
    // FF2 half (+ residual from bf16 x_res) -> out
    k_gemm<EPI_FF2><<<dim3(1176), dim3(256), 0, stream>>>(
        hbuf + to * 1536, ff2_wt, ff2_b, 1536, 3, 1176 / 8, 0,
        nullptr, x_res + to * 384, out + to * 384, nullptr);
  }
}